// Round 1
// baseline (1199.113 us; speedup 1.0000x reference)
//
#include <hip/hip_runtime.h>

// CrossAttention: B=8, S=2048, D=512, K_SIZE=6, all fp32.
// Pipeline:
//   1. dwout = depthwise_conv1d(evo, dw_w, pad(2,3)) + dw_b      [B,S,D] (ws region X)
//   2. Q  = evo @ Wq^T + bq + pos                                 [B,S,D] (ws region Q)
//   3. KV = dwout @ pw_w^T + pw_b                                 [B,S,D] (ws region KV)
//   4. per batch-chunk c:
//        scores = (Q @ KV^T) * 1/sqrt(512)                        [c,S,S] (ws region X, reused)
//        softmax rows in-place
//        out = attn @ KV + KV + evo                               [B,S,D] -> d_out
// All GEMMs: fp32 vector-ALU (no fp32 MFMA on CDNA4), 128x128 tile, BK=16,
// 256 threads, 8x8 per thread with split 64-offset fragments (2-way LDS reads = free).

#define BM 128
#define BN 128
#define BK 16
#define LDT 132  // padded leading dim (floats); 132*4B % 16 == 0 so float4 LDS ok

typedef float4 f4;

__device__ __forceinline__ f4 ld4(const float* p) { return *(const f4*)p; }

// C[m,n] = alpha * sum_k A[m,k] * W[n,k]  (+ bias[n]) (+ pos[(m&posMask)*N + n])
__global__ __launch_bounds__(256, 2)
void gemm_nt_kernel(const float* __restrict__ A, long long sA, int ldA,
                    const float* __restrict__ W, long long sW,
                    float* __restrict__ C, long long sC,
                    int N, int K, float alpha,
                    const float* __restrict__ bias,
                    const float* __restrict__ pos, int posMask)
{
    __shared__ float As[BK][LDT];
    __shared__ float Bs[BK][LDT];
    const int t = threadIdx.x;
    A += (long long)blockIdx.z * sA;
    W += (long long)blockIdx.z * sW;
    C += (long long)blockIdx.z * sC;
    const int m0 = blockIdx.y * BM;
    const int n0 = blockIdx.x * BN;
    const int tx = t & 15, ty = t >> 4;

    float acc[8][8];
#pragma unroll
    for (int i = 0; i < 8; ++i)
#pragma unroll
        for (int j = 0; j < 8; ++j) acc[i][j] = 0.f;

    for (int k0 = 0; k0 < K; k0 += BK) {
#pragma unroll
        for (int i = 0; i < 2; ++i) {
            int idx = t + i * 256;       // 0..511
            int row = idx >> 2;          // 0..127
            int kq  = (idx & 3) << 2;    // 0,4,8,12
            f4 av = ld4(A + (long long)(m0 + row) * ldA + k0 + kq);
            As[kq + 0][row] = av.x; As[kq + 1][row] = av.y;
            As[kq + 2][row] = av.z; As[kq + 3][row] = av.w;
            f4 wv = ld4(W + (long long)(n0 + row) * K + k0 + kq);
            Bs[kq + 0][row] = wv.x; Bs[kq + 1][row] = wv.y;
            Bs[kq + 2][row] = wv.z; Bs[kq + 3][row] = wv.w;
        }
        __syncthreads();
#pragma unroll
        for (int k = 0; k < BK; ++k) {
            float a[8], b[8];
            *(f4*)&a[0] = *(const f4*)&As[k][ty * 4];
            *(f4*)&a[4] = *(const f4*)&As[k][64 + ty * 4];
            *(f4*)&b[0] = *(const f4*)&Bs[k][tx * 4];
            *(f4*)&b[4] = *(const f4*)&Bs[k][64 + tx * 4];
#pragma unroll
            for (int i = 0; i < 8; ++i)
#pragma unroll
                for (int j = 0; j < 8; ++j)
                    acc[i][j] = fmaf(a[i], b[j], acc[i][j]);
        }
        __syncthreads();
    }

#pragma unroll
    for (int ih = 0; ih < 2; ++ih)
#pragma unroll
        for (int ii = 0; ii < 4; ++ii) {
            int m = m0 + ih * 64 + ty * 4 + ii;
#pragma unroll
            for (int jh = 0; jh < 2; ++jh) {
                int n = n0 + jh * 64 + tx * 4;
                int ai = ih * 4 + ii, bj = jh * 4;
                f4 v;
                v.x = acc[ai][bj + 0] * alpha;
                v.y = acc[ai][bj + 1] * alpha;
                v.z = acc[ai][bj + 2] * alpha;
                v.w = acc[ai][bj + 3] * alpha;
                if (bias) {
                    v.x += bias[n + 0]; v.y += bias[n + 1];
                    v.z += bias[n + 2]; v.w += bias[n + 3];
                }
                if (pos) {
                    f4 p = ld4(pos + (long long)(m & posMask) * N + n);
                    v.x += p.x; v.y += p.y; v.z += p.z; v.w += p.w;
                }
                *(f4*)(C + (long long)m * N + n) = v;
            }
        }
}

// C[m,n] = sum_k A[m,k] * Bm[k,n] + add1[m,n] + add2[m,n]
__global__ __launch_bounds__(256, 2)
void gemm_nn_ep_kernel(const float* __restrict__ A, long long sA, int ldA,
                       const float* __restrict__ Bm, long long sB,
                       const float* __restrict__ add1, long long sAdd,
                       const float* __restrict__ add2,
                       float* __restrict__ C, long long sC,
                       int N, int K)
{
    __shared__ float As[BK][LDT];
    __shared__ float Bs[BK][LDT];
    const int t = threadIdx.x;
    A    += (long long)blockIdx.z * sA;
    Bm   += (long long)blockIdx.z * sB;
    add1 += (long long)blockIdx.z * sAdd;
    add2 += (long long)blockIdx.z * sAdd;
    C    += (long long)blockIdx.z * sC;
    const int m0 = blockIdx.y * BM;
    const int n0 = blockIdx.x * BN;
    const int tx = t & 15, ty = t >> 4;

    float acc[8][8];
#pragma unroll
    for (int i = 0; i < 8; ++i)
#pragma unroll
        for (int j = 0; j < 8; ++j) acc[i][j] = 0.f;

    for (int k0 = 0; k0 < K; k0 += BK) {
#pragma unroll
        for (int i = 0; i < 2; ++i) {
            int idx = t + i * 256;
            int row = idx >> 2;
            int kq  = (idx & 3) << 2;
            f4 av = ld4(A + (long long)(m0 + row) * ldA + k0 + kq);
            As[kq + 0][row] = av.x; As[kq + 1][row] = av.y;
            As[kq + 2][row] = av.z; As[kq + 3][row] = av.w;
            // B tile: rows of Bm (k-major), direct copy
            int r  = idx >> 5;        // 0..15
            int c4 = idx & 31;        // 0..31 float4 cols
            f4 bv = ld4(Bm + (long long)(k0 + r) * N + n0 + c4 * 4);
            *(f4*)&Bs[r][c4 * 4] = bv;
        }
        __syncthreads();
#pragma unroll
        for (int k = 0; k < BK; ++k) {
            float a[8], b[8];
            *(f4*)&a[0] = *(const f4*)&As[k][ty * 4];
            *(f4*)&a[4] = *(const f4*)&As[k][64 + ty * 4];
            *(f4*)&b[0] = *(const f4*)&Bs[k][tx * 4];
            *(f4*)&b[4] = *(const f4*)&Bs[k][64 + tx * 4];
#pragma unroll
            for (int i = 0; i < 8; ++i)
#pragma unroll
                for (int j = 0; j < 8; ++j)
                    acc[i][j] = fmaf(a[i], b[j], acc[i][j]);
        }
        __syncthreads();
    }

#pragma unroll
    for (int ih = 0; ih < 2; ++ih)
#pragma unroll
        for (int ii = 0; ii < 4; ++ii) {
            int m = m0 + ih * 64 + ty * 4 + ii;
#pragma unroll
            for (int jh = 0; jh < 2; ++jh) {
                int n = n0 + jh * 64 + tx * 4;
                int ai = ih * 4 + ii, bj = jh * 4;
                long long off = (long long)m * N + n;
                f4 k1 = ld4(add1 + off);
                f4 k2 = ld4(add2 + off);
                f4 v;
                v.x = acc[ai][bj + 0] + k1.x + k2.x;
                v.y = acc[ai][bj + 1] + k1.y + k2.y;
                v.z = acc[ai][bj + 2] + k1.z + k2.z;
                v.w = acc[ai][bj + 3] + k1.w + k2.w;
                *(f4*)(C + off) = v;
            }
        }
}

// depthwise conv1d over S, kernel 6, pad (2,3): y[b,s,d] = dw_b[d] + sum_k x[b,s+k-2,d]*w[d,k]
__global__ __launch_bounds__(256)
void dw_conv_kernel(const float* __restrict__ x, const float* __restrict__ w,
                    const float* __restrict__ bias, float* __restrict__ y)
{
    const long long total = (long long)8 * 2048 * 128;  // float4 count
    long long stride = (long long)gridDim.x * 256;
    for (long long i = (long long)blockIdx.x * 256 + threadIdx.x; i < total; i += stride) {
        int  d4 = (int)(i & 127);         // float4 index in D
        long long bs = i >> 7;            // b*2048 + s
        int  s  = (int)(bs & 2047);
        int  d  = d4 * 4;
        float a0 = bias[d], a1 = bias[d + 1], a2 = bias[d + 2], a3 = bias[d + 3];
#pragma unroll
        for (int k = 0; k < 6; ++k) {
            int ss = s + k - 2;
            if (ss < 0 || ss >= 2048) continue;
            f4 v = ld4(x + ((bs + (long long)(k - 2)) << 9) + d);
            a0 = fmaf(v.x, w[(d + 0) * 6 + k], a0);
            a1 = fmaf(v.y, w[(d + 1) * 6 + k], a1);
            a2 = fmaf(v.z, w[(d + 2) * 6 + k], a2);
            a3 = fmaf(v.w, w[(d + 3) * 6 + k], a3);
        }
        f4 o; o.x = a0; o.y = a1; o.z = a2; o.w = a3;
        *(f4*)(y + (i << 2)) = o;
    }
}

// in-place row softmax, row length 2048, one block per row
__global__ __launch_bounds__(256)
void softmax_rows_kernel(float* __restrict__ p)
{
    float* row = p + ((long long)blockIdx.x << 11);
    const int t = threadIdx.x;
    __shared__ float redMax[4];
    __shared__ float redSum[4];

    f4 x0 = *(const f4*)(row + t * 4);
    f4 x1 = *(const f4*)(row + 1024 + t * 4);
    float m = fmaxf(fmaxf(fmaxf(x0.x, x0.y), fmaxf(x0.z, x0.w)),
                    fmaxf(fmaxf(x1.x, x1.y), fmaxf(x1.z, x1.w)));
#pragma unroll
    for (int off = 32; off > 0; off >>= 1) m = fmaxf(m, __shfl_xor(m, off));
    if ((t & 63) == 0) redMax[t >> 6] = m;
    __syncthreads();
    m = fmaxf(fmaxf(redMax[0], redMax[1]), fmaxf(redMax[2], redMax[3]));

    float e[8];
    e[0] = __expf(x0.x - m); e[1] = __expf(x0.y - m);
    e[2] = __expf(x0.z - m); e[3] = __expf(x0.w - m);
    e[4] = __expf(x1.x - m); e[5] = __expf(x1.y - m);
    e[6] = __expf(x1.z - m); e[7] = __expf(x1.w - m);
    float ssum = ((e[0] + e[1]) + (e[2] + e[3])) + ((e[4] + e[5]) + (e[6] + e[7]));
#pragma unroll
    for (int off = 32; off > 0; off >>= 1) ssum += __shfl_xor(ssum, off);
    if ((t & 63) == 0) redSum[t >> 6] = ssum;
    __syncthreads();
    ssum = (redSum[0] + redSum[1]) + (redSum[2] + redSum[3]);
    float inv = 1.0f / ssum;

    f4 o0, o1;
    o0.x = e[0] * inv; o0.y = e[1] * inv; o0.z = e[2] * inv; o0.w = e[3] * inv;
    o1.x = e[4] * inv; o1.y = e[5] * inv; o1.z = e[6] * inv; o1.w = e[7] * inv;
    *(f4*)(row + t * 4) = o0;
    *(f4*)(row + 1024 + t * 4) = o1;
}

extern "C" void kernel_launch(void* const* d_in, const int* in_sizes, int n_in,
                              void* d_out, int out_size, void* d_ws, size_t ws_size,
                              hipStream_t stream)
{
    const float* evo  = (const float*)d_in[0];
    const float* Wq   = (const float*)d_in[1];
    const float* bq   = (const float*)d_in[2];
    const float* dw_w = (const float*)d_in[3];
    const float* dw_b = (const float*)d_in[4];
    const float* pw_w = (const float*)d_in[5];
    const float* pw_b = (const float*)d_in[6];
    const float* pos  = (const float*)d_in[7];
    float* out = (float*)d_out;

    const int Bb = 8, S = 2048, D = 512;
    const long long szQ = (long long)Bb * S * D;  // 8.39M floats

    float* Q  = (float*)d_ws;
    float* KV = Q + szQ;
    float* X  = KV + szQ;  // dwout first, then reused for scores chunks

    // batch chunk count from workspace (pure function of ws_size -> capture-safe)
    long long wsFloats = (long long)(ws_size / 4);
    long long Xfloats  = wsFloats - 2 * szQ;
    int c = 1;
    if (Xfloats > 0) {
        long long cc = Xfloats / ((long long)S * S);
        c = (cc < 1) ? 1 : (cc > 8 ? 8 : (int)cc);
    }

    const float scale = 0.04419417382415922f;  // 1/sqrt(512)

    // 1. depthwise conv -> X
    dw_conv_kernel<<<2048, 256, 0, stream>>>(evo, dw_w, dw_b, X);

    // 2. Q = evo @ Wq^T + bq + pos
    gemm_nt_kernel<<<dim3(D / BN, (Bb * S) / BM, 1), 256, 0, stream>>>(
        evo, 0, D, Wq, 0, Q, 0, D, D, 1.0f, bq, pos, S - 1);

    // 3. KV = dwout @ pw_w^T + pw_b
    gemm_nt_kernel<<<dim3(D / BN, (Bb * S) / BM, 1), 256, 0, stream>>>(
        X, 0, D, pw_w, 0, KV, 0, D, D, 1.0f, pw_b, nullptr, 0);

    // 4. attention, batch-chunked through X
    for (int b0 = 0; b0 < Bb; b0 += c) {
        int cc = (Bb - b0 < c) ? (Bb - b0) : c;
        long long off = (long long)b0 * S * D;
        // scores = scale * Q @ KV^T   [cc, S, S]
        gemm_nt_kernel<<<dim3(S / BN, S / BM, cc), 256, 0, stream>>>(
            Q + off, (long long)S * D, D, KV + off, (long long)S * D,
            X, (long long)S * S, S, D, scale, nullptr, nullptr, 0);
        // softmax rows in place
        softmax_rows_kernel<<<cc * S, 256, 0, stream>>>(X);
        // out = attn @ KV + KV + evo
        gemm_nn_ep_kernel<<<dim3(D / BN, S / BM, cc), 256, 0, stream>>>(
            X, (long long)S * S, S, KV + off, (long long)S * D,
            KV + off, (long long)S * D, evo + off,
            out + off, (long long)S * D, D, D * 4 /*unused*/ == 0 ? S : S);
    }
}

// Round 2
// 418.818 us; speedup vs baseline: 2.8631x; 2.8631x over previous
//
#include <hip/hip_runtime.h>

// CrossAttention B=8,S=2048,D=512 — MFMA bf16 rewrite.
//  Q  = evo @ Wq^T + bq + pos        (bf16x3 inputs, write Q hi)
//  KV = dwconv(evo) @ pw_w^T + pw_b  (bf16x3 inputs, write KV hi/lo + KV^T hi)
//  scores = scale * Q @ KV^T -> bf16 ; softmax rows in place (bf16)
//  out = attn @ KV + (KVhi+KVlo) + evo  (fp32 out)
// GEMM: m97 structure — 128x128 tile, BK=32, 4 waves, mfma_f32_16x16x32_bf16,
// global_load_lds width 16 (wave-uniform LDS base + lane*16, per-lane global src).

typedef unsigned short ushort_t;
typedef __attribute__((ext_vector_type(8))) short short8;
typedef __attribute__((ext_vector_type(8))) unsigned short u16x8;
typedef __attribute__((ext_vector_type(4))) float f32x4;
typedef float4 f4;

__device__ __forceinline__ float bf2f(ushort_t h) {
    union { unsigned u; float f; } v; v.u = ((unsigned)h) << 16; return v.f;
}
__device__ __forceinline__ ushort_t f2bf(float f) {
    union { float f; unsigned u; } v; v.f = f;
    unsigned r = (v.u + 0x7FFFu + ((v.u >> 16) & 1u)) >> 16;
    return (ushort_t)r;
}

__device__ __forceinline__ void gld_lds16(const void* g, void* l) {
    __builtin_amdgcn_global_load_lds((const __attribute__((address_space(1))) void*)g,
                                     (__attribute__((address_space(3))) void*)l, 16, 0, 0);
}

// NT GEMM: A [M,K] row-major bf16 (hi[,lo]), B [N,K] row-major bf16 (hi[,lo]).
// EPI: 0=Q(+bias+pos, write Ch), 1=KV(+bias, write Ch,Cl,CTh), 2=scores(*alpha, bf16 Ch),
//      3=PV(+ addH+addL+addF, fp32 Cf)
template<int X3, int EPI>
__global__ __launch_bounds__(256)
void mfma_nt(const ushort_t* __restrict__ Ah, const ushort_t* __restrict__ Al, long long sA, int ldA,
             const ushort_t* __restrict__ Bh, const ushort_t* __restrict__ Bl, long long sB, int ldB,
             int N, int K, float alpha,
             const float* __restrict__ bias, const float* __restrict__ pos,
             ushort_t* __restrict__ Ch, ushort_t* __restrict__ Cl, ushort_t* __restrict__ CTh,
             long long sC,
             float* __restrict__ Cf,
             const ushort_t* __restrict__ addH, const ushort_t* __restrict__ addL,
             const float* __restrict__ addF, long long sAdd)
{
    __shared__ __align__(16) ushort_t lds[X3 ? 16384 : 8192];
    ushort_t* lAh = lds;
    ushort_t* lBh = lds + 4096;
    ushort_t* lAl = lds + (X3 ? 8192 : 0);
    ushort_t* lBl = lds + (X3 ? 12288 : 0);

    const int t = threadIdx.x;
    const int w = t >> 6, lane = t & 63;
    const int z = blockIdx.z;
    Ah += (long long)z * sA;
    Bh += (long long)z * sB;
    if (X3) { Al += (long long)z * sA; Bl += (long long)z * sB; }

    const int m0 = blockIdx.y * 128, n0 = blockIdx.x * 128;
    const int wr = w >> 1, wc = w & 1;
    const int fr = lane & 15, kg = lane >> 4;
    const int srow = lane >> 2;          // staging: row within 16-row group
    const int scol = (lane & 3) * 8;     // staging: bf16 col offset (16B chunk)

    const f32x4 zero = {0.f, 0.f, 0.f, 0.f};
    f32x4 acc[4][4];
#pragma unroll
    for (int i = 0; i < 4; ++i)
#pragma unroll
        for (int j = 0; j < 4; ++j) acc[i][j] = zero;

    for (int k0 = 0; k0 < K; k0 += 32) {
#pragma unroll
        for (int i = 0; i < 2; ++i) {
            const int g = w * 2 + i;                 // 1KB group 0..7
            const int row = g * 16 + srow;           // tile row 0..127
            gld_lds16(Ah + (long long)(m0 + row) * ldA + k0 + scol, &lAh[g * 512]);
            gld_lds16(Bh + (long long)(n0 + row) * ldB + k0 + scol, &lBh[g * 512]);
            if (X3) {
                gld_lds16(Al + (long long)(m0 + row) * ldA + k0 + scol, &lAl[g * 512]);
                gld_lds16(Bl + (long long)(n0 + row) * ldB + k0 + scol, &lBl[g * 512]);
            }
        }
        __syncthreads();

        short8 aH[4], aL[4];
#pragma unroll
        for (int fm = 0; fm < 4; ++fm) {
            const int ar = (wr * 64 + fm * 16 + fr) * 32 + kg * 8;
            aH[fm] = *(const short8*)&lAh[ar];
            if (X3) aL[fm] = *(const short8*)&lAl[ar];
        }
#pragma unroll
        for (int fn = 0; fn < 4; ++fn) {
            const int br = (wc * 64 + fn * 16 + fr) * 32 + kg * 8;
            short8 bH = *(const short8*)&lBh[br];
#pragma unroll
            for (int fm = 0; fm < 4; ++fm)
                acc[fm][fn] = __builtin_amdgcn_mfma_f32_16x16x32_bf16(aH[fm], bH, acc[fm][fn], 0, 0, 0);
            if (X3) {
                short8 bL = *(const short8*)&lBl[br];
#pragma unroll
                for (int fm = 0; fm < 4; ++fm) {
                    acc[fm][fn] = __builtin_amdgcn_mfma_f32_16x16x32_bf16(aH[fm], bL, acc[fm][fn], 0, 0, 0);
                    acc[fm][fn] = __builtin_amdgcn_mfma_f32_16x16x32_bf16(aL[fm], bH, acc[fm][fn], 0, 0, 0);
                }
            }
        }
        __syncthreads();
    }

    // Epilogue. C/D frag mapping (guide m89/m91): m = (lane>>4)*4 + r, n = lane&15.
#pragma unroll
    for (int fm = 0; fm < 4; ++fm)
#pragma unroll
    for (int fn = 0; fn < 4; ++fn)
#pragma unroll
    for (int r = 0; r < 4; ++r) {
        const int m = m0 + wr * 64 + fm * 16 + kg * 4 + r;
        const int n = n0 + wc * 64 + fn * 16 + fr;
        float v = acc[fm][fn][r];
        const long long idx = (long long)m * N + n;
        if (EPI == 0) {
            v += bias[n] + pos[(long long)(m & 2047) * N + n];
            Ch[idx] = f2bf(v);
        } else if (EPI == 1) {
            v += bias[n];
            ushort_t hi = f2bf(v);
            Ch[idx] = hi;
            Cl[idx] = f2bf(v - bf2f(hi));
            CTh[(long long)(m >> 11) * (512LL * 2048) + (long long)n * 2048 + (m & 2047)] = hi;
        } else if (EPI == 2) {
            Ch[(long long)z * sC + idx] = f2bf(v * alpha);
        } else {
            const long long o = (long long)z * sAdd + idx;
            v += bf2f(addH[o]) + bf2f(addL[o]) + addF[o];
            Cf[o] = v;
        }
    }
}

// fp32 -> (bf16 hi, bf16 lo) pairs, vectorized by 4
__global__ __launch_bounds__(256)
void cvt_pairs(const float* __restrict__ in, ushort_t* __restrict__ hi,
               ushort_t* __restrict__ lo, long long n4)
{
    const long long stride = (long long)gridDim.x * 256;
    for (long long i = (long long)blockIdx.x * 256 + threadIdx.x; i < n4; i += stride) {
        f4 v = *(const f4*)(in + (i << 2));
        ushort4 h, l;
        h.x = f2bf(v.x); l.x = f2bf(v.x - bf2f(h.x));
        h.y = f2bf(v.y); l.y = f2bf(v.y - bf2f(h.y));
        h.z = f2bf(v.z); l.z = f2bf(v.z - bf2f(h.z));
        h.w = f2bf(v.w); l.w = f2bf(v.w - bf2f(h.w));
        *(ushort4*)&hi[i << 2] = h;
        *(ushort4*)&lo[i << 2] = l;
    }
}

// depthwise conv1d K=6, pad(2,3) + bias -> bf16 hi/lo pairs
__global__ __launch_bounds__(256)
void dw_conv_pairs(const float* __restrict__ x, const float* __restrict__ w,
                   const float* __restrict__ bias,
                   ushort_t* __restrict__ hi, ushort_t* __restrict__ lo)
{
    const long long total = 8LL * 2048 * 128;  // float4 count
    const long long stride = (long long)gridDim.x * 256;
    for (long long i = (long long)blockIdx.x * 256 + threadIdx.x; i < total; i += stride) {
        const int d4 = (int)(i & 127);
        const long long bs = i >> 7;
        const int s = (int)(bs & 2047);
        const int d = d4 * 4;
        float a0 = bias[d], a1 = bias[d + 1], a2 = bias[d + 2], a3 = bias[d + 3];
#pragma unroll
        for (int k = 0; k < 6; ++k) {
            int ss = s + k - 2;
            if (ss < 0 || ss >= 2048) continue;
            f4 v = *(const f4*)(x + ((bs + (long long)(k - 2)) << 9) + d);
            a0 = fmaf(v.x, w[(d + 0) * 6 + k], a0);
            a1 = fmaf(v.y, w[(d + 1) * 6 + k], a1);
            a2 = fmaf(v.z, w[(d + 2) * 6 + k], a2);
            a3 = fmaf(v.w, w[(d + 3) * 6 + k], a3);
        }
        ushort4 h, l;
        h.x = f2bf(a0); l.x = f2bf(a0 - bf2f(h.x));
        h.y = f2bf(a1); l.y = f2bf(a1 - bf2f(h.y));
        h.z = f2bf(a2); l.z = f2bf(a2 - bf2f(h.z));
        h.w = f2bf(a3); l.w = f2bf(a3 - bf2f(h.w));
        *(ushort4*)&hi[i << 2] = h;
        *(ushort4*)&lo[i << 2] = l;
    }
}

// in-place softmax over bf16 rows of length 2048; one block (256 thr) per row
__global__ __launch_bounds__(256)
void softmax_bf16(ushort_t* __restrict__ p)
{
    ushort_t* row = p + ((long long)blockIdx.x << 11);
    const int t = threadIdx.x;
    __shared__ float redMax[4];
    __shared__ float redSum[4];

    u16x8 u = *(const u16x8*)(row + t * 8);
    float x[8];
#pragma unroll
    for (int i = 0; i < 8; ++i) x[i] = bf2f(u[i]);

    float m = x[0];
#pragma unroll
    for (int i = 1; i < 8; ++i) m = fmaxf(m, x[i]);
#pragma unroll
    for (int off = 32; off > 0; off >>= 1) m = fmaxf(m, __shfl_xor(m, off));
    if ((t & 63) == 0) redMax[t >> 6] = m;
    __syncthreads();
    m = fmaxf(fmaxf(redMax[0], redMax[1]), fmaxf(redMax[2], redMax[3]));

    float e[8], s = 0.f;
#pragma unroll
    for (int i = 0; i < 8; ++i) { e[i] = __expf(x[i] - m); s += e[i]; }
#pragma unroll
    for (int off = 32; off > 0; off >>= 1) s += __shfl_xor(s, off);
    if ((t & 63) == 0) redSum[t >> 6] = s;
    __syncthreads();
    s = (redSum[0] + redSum[1]) + (redSum[2] + redSum[3]);
    const float inv = 1.0f / s;

#pragma unroll
    for (int i = 0; i < 8; ++i) u[i] = f2bf(e[i] * inv);
    *(u16x8*)(row + t * 8) = u;
}

extern "C" void kernel_launch(void* const* d_in, const int* in_sizes, int n_in,
                              void* d_out, int out_size, void* d_ws, size_t ws_size,
                              hipStream_t stream)
{
    const float* evo  = (const float*)d_in[0];
    const float* Wq   = (const float*)d_in[1];
    const float* bq   = (const float*)d_in[2];
    const float* dw_w = (const float*)d_in[3];
    const float* dw_b = (const float*)d_in[4];
    const float* pw_w = (const float*)d_in[5];
    const float* pw_b = (const float*)d_in[6];
    const float* pos  = (const float*)d_in[7];
    float* out = (float*)d_out;

    const long long BSD = 8LL * 2048 * 512;   // 8,388,608
    const long long DD  = 512LL * 512;        // 262,144
    const long long SD  = 2048LL * 512;       // 1,048,576 (== D*S)
    const long long SS  = 2048LL * 2048;      // 4,194,304

    ushort_t* QHi  = (ushort_t*)d_ws;
    ushort_t* KVHi = QHi + BSD;
    ushort_t* KVLo = KVHi + BSD;
    ushort_t* KVT  = KVLo + BSD;
    ushort_t* WqHi = KVT + BSD;
    ushort_t* WqLo = WqHi + DD;
    ushort_t* pwHi = WqLo + DD;
    ushort_t* pwLo = pwHi + DD;
    ushort_t* X    = pwLo + DD;   // byte offset 69,206,016 from ws base

    // chunk count from remaining ws (pure function of ws_size -> capture-safe)
    long long Xbytes = (long long)ws_size - 69206016LL;
    long long cRaw = Xbytes / (SS * 2);
    int c;
    if (cRaw >= 8) c = 8; else if (cRaw >= 4) c = 4; else if (cRaw >= 2) c = 2; else c = 1;

    ushort_t* pairA = X;         // evo pairs, then dw pairs (sequential reuse)
    ushort_t* pairB = X + BSD;

    // 1. weight + evo conversions
    cvt_pairs<<<256, 256, 0, stream>>>(Wq, WqHi, WqLo, DD / 4);
    cvt_pairs<<<256, 256, 0, stream>>>(pw_w, pwHi, pwLo, DD / 4);
    cvt_pairs<<<2048, 256, 0, stream>>>(evo, pairA, pairB, BSD / 4);

    // 2. Q = evo @ Wq^T + bq + pos   (bf16x3)
    mfma_nt<1, 0><<<dim3(4, 128, 1), 256, 0, stream>>>(
        pairA, pairB, 0LL, 512, WqHi, WqLo, 0LL, 512, 512, 512, 1.f,
        bq, pos, QHi, nullptr, nullptr, 0LL, nullptr, nullptr, nullptr, nullptr, 0LL);

    // 3. depthwise conv -> pairs (overwrites evo pairs)
    dw_conv_pairs<<<2048, 256, 0, stream>>>(evo, dw_w, dw_b, pairA, pairB);

    // 4. KV = dwout @ pw_w^T + pw_b  (bf16x3) -> KV hi/lo + KV^T hi
    mfma_nt<1, 1><<<dim3(4, 128, 1), 256, 0, stream>>>(
        pairA, pairB, 0LL, 512, pwHi, pwLo, 0LL, 512, 512, 512, 1.f,
        pw_b, nullptr, KVHi, KVLo, KVT, 0LL, nullptr, nullptr, nullptr, nullptr, 0LL);

    // 5. attention, batch-chunked through X
    const float scale = 0.04419417382415922f;  // 1/sqrt(512)
    for (int b0 = 0; b0 < 8; b0 += c) {
        const int cc = (8 - b0 < c) ? (8 - b0) : c;
        const long long o = (long long)b0 * SD;
        // scores = scale * Q @ KV^T -> bf16 in X
        mfma_nt<0, 2><<<dim3(16, 16, cc), 256, 0, stream>>>(
            QHi + o, nullptr, SD, 512, KVHi + o, nullptr, SD, 512, 2048, 512, scale,
            nullptr, nullptr, X, nullptr, nullptr, SS, nullptr, nullptr, nullptr, nullptr, 0LL);
        // softmax rows in place (bf16)
        softmax_bf16<<<cc * 2048, 256, 0, stream>>>(X);
        // out = attn @ KV + (KVhi+KVlo) + evo
        mfma_nt<0, 3><<<dim3(4, 16, cc), 256, 0, stream>>>(
            X, nullptr, SS, 2048, KVT + o, nullptr, SD, 2048, 512, 2048, 1.f,
            nullptr, nullptr, nullptr, nullptr, nullptr, 0LL,
            out + o, KVHi + o, KVLo + o, evo + o, SD);
    }
}

// Round 3
// 304.696 us; speedup vs baseline: 3.9354x; 1.3745x over previous
//
#include <hip/hip_runtime.h>

// CrossAttention B=8,S=2048,D=512 — MFMA bf16, lean preprocessing.
//  cvt2:    Wq, pw_w -> bf16
//  dwconv:  evo fp32 -> dwout bf16 (reg sliding window, 8 out/thread)
//  Q  = evo @ Wq^T + bq + pos      (A reg-staged fp32->bf16, B gload_lds)
//  KV = dwout @ pw^T + pw_b        -> KVhi, KVlo (fp32-accurate pair), KVT
//  per chunk: scores=scale*Q@KV^T (bf16) ; softmax rows ; out=attn@KV+KV+evo
// GEMM core: m97 structure — 128x128 tile, BK=32, 4 waves, mfma_f32_16x16x32_bf16.

typedef unsigned short ushort_t;
typedef __attribute__((ext_vector_type(8))) short short8;
typedef __attribute__((ext_vector_type(8))) unsigned short u16x8;
typedef __attribute__((ext_vector_type(4))) float f32x4;
typedef float4 f4;

__device__ __forceinline__ float bf2f(ushort_t h) {
    union { unsigned u; float f; } v; v.u = ((unsigned)h) << 16; return v.f;
}
__device__ __forceinline__ ushort_t f2bf(float f) {
    union { float f; unsigned u; } v; v.f = f;
    unsigned r = (v.u + 0x7FFFu + ((v.u >> 16) & 1u)) >> 16;
    return (ushort_t)r;
}

__device__ __forceinline__ void gld_lds16(const void* g, void* l) {
    __builtin_amdgcn_global_load_lds((const __attribute__((address_space(1))) void*)g,
                                     (__attribute__((address_space(3))) void*)l, 16, 0, 0);
}

// NT GEMM: A [M,K] (bf16, or fp32 reg-staged if AF32), B [N,K] bf16 row-major.
// EPI: 0=Q(+bias+pos -> bf16), 1=KV(+bias -> hi,lo,T), 2=scores(*alpha -> bf16),
//      3=PV(+addH+addL+addF -> fp32)
template<int AF32, int EPI>
__global__ __launch_bounds__(256)
void mfma_nt(const void* __restrict__ Aptr, long long sA, int ldA,
             const ushort_t* __restrict__ Bh, long long sB, int ldB,
             int N, int K, float alpha,
             const float* __restrict__ bias, const float* __restrict__ pos,
             ushort_t* __restrict__ Ch, ushort_t* __restrict__ Cl, ushort_t* __restrict__ CTh,
             long long sC,
             float* __restrict__ Cf,
             const ushort_t* __restrict__ addH, const ushort_t* __restrict__ addL,
             const float* __restrict__ addF, long long sAdd)
{
    __shared__ __align__(16) ushort_t lds[8192];
    ushort_t* lAh = lds;
    ushort_t* lBh = lds + 4096;

    const int t = threadIdx.x;
    const int w = t >> 6, lane = t & 63;
    const int z = blockIdx.z;
    const ushort_t* Ab = (const ushort_t*)Aptr + (long long)z * sA;
    const float*    Af = (const float*)Aptr    + (long long)z * sA;
    Bh += (long long)z * sB;

    const int m0 = blockIdx.y * 128, n0 = blockIdx.x * 128;
    const int wr = w >> 1, wc = w & 1;
    const int fr = lane & 15, kg = lane >> 4;
    const int srow = lane >> 2;          // staging: row within 16-row group
    const int scol = (lane & 3) * 8;     // staging: bf16/fp32 col offset (8 elems)

    const f32x4 zero = {0.f, 0.f, 0.f, 0.f};
    f32x4 acc[4][4];
#pragma unroll
    for (int i = 0; i < 4; ++i)
#pragma unroll
        for (int j = 0; j < 4; ++j) acc[i][j] = zero;

    for (int k0 = 0; k0 < K; k0 += 32) {
#pragma unroll
        for (int i = 0; i < 2; ++i) {
            const int g = w * 2 + i;                 // 1KB group 0..7
            const int row = g * 16 + srow;           // tile row 0..127
            if (AF32) {
                const float* p = Af + (long long)(m0 + row) * ldA + k0 + scol;
                f4 v0 = *(const f4*)p;
                f4 v1 = *(const f4*)(p + 4);
                u16x8 o;
                o[0] = f2bf(v0.x); o[1] = f2bf(v0.y); o[2] = f2bf(v0.z); o[3] = f2bf(v0.w);
                o[4] = f2bf(v1.x); o[5] = f2bf(v1.y); o[6] = f2bf(v1.z); o[7] = f2bf(v1.w);
                *(u16x8*)&lAh[g * 512 + srow * 32 + scol] = o;
            } else {
                gld_lds16(Ab + (long long)(m0 + row) * ldA + k0 + scol, &lAh[g * 512]);
            }
            gld_lds16(Bh + (long long)(n0 + row) * ldB + k0 + scol, &lBh[g * 512]);
        }
        __syncthreads();

        short8 aH[4];
#pragma unroll
        for (int fm = 0; fm < 4; ++fm)
            aH[fm] = *(const short8*)&lAh[(wr * 64 + fm * 16 + fr) * 32 + kg * 8];
#pragma unroll
        for (int fn = 0; fn < 4; ++fn) {
            short8 bH = *(const short8*)&lBh[(wc * 64 + fn * 16 + fr) * 32 + kg * 8];
#pragma unroll
            for (int fm = 0; fm < 4; ++fm)
                acc[fm][fn] = __builtin_amdgcn_mfma_f32_16x16x32_bf16(aH[fm], bH, acc[fm][fn], 0, 0, 0);
        }
        __syncthreads();
    }

    // C/D frag mapping (m89/m91): m = (lane>>4)*4 + r, n = lane&15.
#pragma unroll
    for (int fm = 0; fm < 4; ++fm)
#pragma unroll
    for (int fn = 0; fn < 4; ++fn)
#pragma unroll
    for (int r = 0; r < 4; ++r) {
        const int m = m0 + wr * 64 + fm * 16 + kg * 4 + r;
        const int n = n0 + wc * 64 + fn * 16 + fr;
        float v = acc[fm][fn][r];
        const long long idx = (long long)m * N + n;
        if (EPI == 0) {
            v += bias[n] + pos[(long long)(m & 2047) * N + n];
            Ch[idx] = f2bf(v);
        } else if (EPI == 1) {
            v += bias[n];
            ushort_t hi = f2bf(v);
            Ch[idx] = hi;
            Cl[idx] = f2bf(v - bf2f(hi));
            CTh[(long long)(m >> 11) * (512LL * 2048) + (long long)n * 2048 + (m & 2047)] = hi;
        } else if (EPI == 2) {
            Ch[(long long)z * sC + idx] = f2bf(v * alpha);
        } else {
            const long long o = (long long)z * sAdd + idx;
            v += bf2f(addH[o]) + bf2f(addL[o]) + addF[o];
            Cf[o] = v;
        }
    }
}

// two fp32->bf16 conversions (Wq, pw_w), 65536 float4 each
__global__ __launch_bounds__(256)
void cvt2_bf16(const float* __restrict__ a, ushort_t* __restrict__ ao,
               const float* __restrict__ b, ushort_t* __restrict__ bo)
{
    int i = blockIdx.x * 256 + threadIdx.x;   // 0..131071
    const float* src = (i < 65536) ? a : b;
    ushort_t* dst = (i < 65536) ? ao : bo;
    int j = i & 65535;
    f4 v = *(const f4*)(src + (long long)j * 4);
    ushort4 o;
    o.x = f2bf(v.x); o.y = f2bf(v.y); o.z = f2bf(v.z); o.w = f2bf(v.w);
    *(ushort4*)&dst[(long long)j * 4] = o;
}

// depthwise conv1d K=6 pad(2,3) + bias, fp32 in -> bf16 out.
// thread = (b, 8-row s-chunk, float4 d-col); 13-row register window, 8 outputs.
__global__ __launch_bounds__(256)
void dwconv_bf16(const float* __restrict__ x, const float* __restrict__ w,
                 const float* __restrict__ bias, ushort_t* __restrict__ y)
{
    const int tid = blockIdx.x * 256 + threadIdx.x;  // 262144 total
    const int d4 = tid & 127;
    const int rest = tid >> 7;
    const int sc = rest & 255;
    const int b = rest >> 8;
    const int s0 = sc * 8;
    const float* xb = x + ((long long)b * 2048) * 512 + d4 * 4;

    f4 win[13];
#pragma unroll
    for (int j = 0; j < 13; ++j) {
        int r = s0 + j - 2;
        int rc = r < 0 ? 0 : (r > 2047 ? 2047 : r);
        f4 v = *(const f4*)(xb + (long long)rc * 512);
        if (r < 0 || r > 2047) { v.x = 0.f; v.y = 0.f; v.z = 0.f; v.w = 0.f; }
        win[j] = v;
    }
    float wk[4][6];
#pragma unroll
    for (int dd = 0; dd < 4; ++dd)
#pragma unroll
        for (int k = 0; k < 6; ++k) wk[dd][k] = w[(d4 * 4 + dd) * 6 + k];
    const f4 bs4 = *(const f4*)(bias + d4 * 4);

    ushort_t* yb = y + ((long long)b * 2048 + s0) * 512 + d4 * 4;
#pragma unroll
    for (int u = 0; u < 8; ++u) {
        float a0 = bs4.x, a1 = bs4.y, a2 = bs4.z, a3 = bs4.w;
#pragma unroll
        for (int k = 0; k < 6; ++k) {
            f4 v = win[u + k];
            a0 = fmaf(v.x, wk[0][k], a0);
            a1 = fmaf(v.y, wk[1][k], a1);
            a2 = fmaf(v.z, wk[2][k], a2);
            a3 = fmaf(v.w, wk[3][k], a3);
        }
        ushort4 o;
        o.x = f2bf(a0); o.y = f2bf(a1); o.z = f2bf(a2); o.w = f2bf(a3);
        *(ushort4*)(yb + (long long)u * 512) = o;
    }
}

// in-place softmax over bf16 rows of length 2048; one block (256 thr) per row
__global__ __launch_bounds__(256)
void softmax_bf16(ushort_t* __restrict__ p)
{
    ushort_t* row = p + ((long long)blockIdx.x << 11);
    const int t = threadIdx.x;
    __shared__ float redMax[4];
    __shared__ float redSum[4];

    u16x8 u = *(const u16x8*)(row + t * 8);
    float x[8];
#pragma unroll
    for (int i = 0; i < 8; ++i) x[i] = bf2f(u[i]);

    float m = x[0];
#pragma unroll
    for (int i = 1; i < 8; ++i) m = fmaxf(m, x[i]);
#pragma unroll
    for (int off = 32; off > 0; off >>= 1) m = fmaxf(m, __shfl_xor(m, off));
    if ((t & 63) == 0) redMax[t >> 6] = m;
    __syncthreads();
    m = fmaxf(fmaxf(redMax[0], redMax[1]), fmaxf(redMax[2], redMax[3]));

    float e[8], s = 0.f;
#pragma unroll
    for (int i = 0; i < 8; ++i) { e[i] = __expf(x[i] - m); s += e[i]; }
#pragma unroll
    for (int off = 32; off > 0; off >>= 1) s += __shfl_xor(s, off);
    if ((t & 63) == 0) redSum[t >> 6] = s;
    __syncthreads();
    s = (redSum[0] + redSum[1]) + (redSum[2] + redSum[3]);
    const float inv = 1.0f / s;

#pragma unroll
    for (int i = 0; i < 8; ++i) u[i] = f2bf(e[i] * inv);
    *(u16x8*)(row + t * 8) = u;
}

extern "C" void kernel_launch(void* const* d_in, const int* in_sizes, int n_in,
                              void* d_out, int out_size, void* d_ws, size_t ws_size,
                              hipStream_t stream)
{
    const float* evo  = (const float*)d_in[0];
    const float* Wq   = (const float*)d_in[1];
    const float* bq   = (const float*)d_in[2];
    const float* dw_w = (const float*)d_in[3];
    const float* dw_b = (const float*)d_in[4];
    const float* pw_w = (const float*)d_in[5];
    const float* pw_b = (const float*)d_in[6];
    const float* pos  = (const float*)d_in[7];
    float* out = (float*)d_out;

    const long long BSD = 8LL * 2048 * 512;   // 8,388,608
    const long long DD  = 512LL * 512;        // 262,144
    const long long SD  = 2048LL * 512;
    const long long SS  = 2048LL * 2048;

    ushort_t* QHi  = (ushort_t*)d_ws;
    ushort_t* KVHi = QHi + BSD;
    ushort_t* KVLo = KVHi + BSD;
    ushort_t* KVT  = KVLo + BSD;
    ushort_t* WqB  = KVT + BSD;
    ushort_t* pwB  = WqB + DD;
    ushort_t* X    = pwB + DD;    // byte offset 68,157,440; holds dwout, then scores

    // chunk count (pure function of ws_size -> capture-safe)
    long long Xbytes = (long long)ws_size - 68157440LL;
    long long cRaw = Xbytes / (SS * 2);
    int c;
    if (cRaw >= 8) c = 8; else if (cRaw >= 4) c = 4; else if (cRaw >= 2) c = 2; else c = 1;

    ushort_t* dwout = X;  // dead after KV GEMM; scores reuse the region

    // 1. weights -> bf16
    cvt2_bf16<<<512, 256, 0, stream>>>(Wq, WqB, pw_w, pwB);

    // 2. depthwise conv -> bf16
    dwconv_bf16<<<1024, 256, 0, stream>>>(evo, dw_w, dw_b, dwout);

    // 3. Q = evo @ Wq^T + bq + pos (A reg-staged from fp32)
    mfma_nt<1, 0><<<dim3(4, 128, 1), 256, 0, stream>>>(
        evo, 0LL, 512, WqB, 0LL, 512, 512, 512, 1.f,
        bq, pos, QHi, nullptr, nullptr, 0LL, nullptr, nullptr, nullptr, nullptr, 0LL);

    // 4. KV = dwout @ pw^T + pw_b -> KVhi/KVlo + KVT
    mfma_nt<0, 1><<<dim3(4, 128, 1), 256, 0, stream>>>(
        dwout, 0LL, 512, pwB, 0LL, 512, 512, 512, 1.f,
        pw_b, nullptr, KVHi, KVLo, KVT, 0LL, nullptr, nullptr, nullptr, nullptr, 0LL);

    // 5. attention, batch-chunked through X
    const float scale = 0.04419417382415922f;  // 1/sqrt(512)
    for (int b0 = 0; b0 < 8; b0 += c) {
        const int cc = (8 - b0 < c) ? (8 - b0) : c;
        const long long o = (long long)b0 * SD;
        mfma_nt<0, 2><<<dim3(16, 16, cc), 256, 0, stream>>>(
            QHi + o, SD, 512, KVHi + o, SD, 512, 2048, 512, scale,
            nullptr, nullptr, X, nullptr, nullptr, SS, nullptr, nullptr, nullptr, nullptr, 0LL);
        softmax_bf16<<<cc * 2048, 256, 0, stream>>>(X);
        mfma_nt<0, 3><<<dim3(4, 16, cc), 256, 0, stream>>>(
            X, SS, 2048, KVT + o, SD, 2048, 512, 2048, 1.f,
            nullptr, nullptr, nullptr, nullptr, nullptr, 0LL,
            out + o, KVHi + o, KVLo + o, evo + o, SD);
    }
}

// Round 9
// 304.232 us; speedup vs baseline: 3.9414x; 1.0015x over previous
//
#include <hip/hip_runtime.h>

// CrossAttention B=8,S=2048,D=512 — MFMA bf16.
//  Q  = evo @ Wq^T + bq + pos      (m97-structure kernel, A reg-staged fp32->bf16)
//  KV = dwconv(evo) @ pw^T + pw_b  (m97-structure kernel) -> KVhi, KVlo, KVT
//  scores = scale * Q @ KV^T (bf16) ; softmax ; out = attn @ KV + KV + evo
//  scores+PV: 256x256-tile 8-wave 4-phase-per-K-tile pipelined kernel.
//  RACE FIX (r8): counted vmcnt(8) waits moved to END of P2/P4 BEFORE the
//  closing barrier (plus prologue WAITV8+BAR). A buffer's loads must be
//  vmcnt-complete in EVERY wave before the barrier that precedes any wave's
//  ds_read of that buffer — the old schedule waited after the barrier, so
//  other waves' stages were not yet visible (first-tile reads hit
//  uninitialized LDS -> NaN).

typedef unsigned short ushort_t;
typedef __attribute__((ext_vector_type(8))) short short8;
typedef __attribute__((ext_vector_type(8))) unsigned short u16x8;
typedef __attribute__((ext_vector_type(4))) float f32x4;
typedef float4 f4;

__device__ __forceinline__ float bf2f(ushort_t h) {
    union { unsigned u; float f; } v; v.u = ((unsigned)h) << 16; return v.f;
}
__device__ __forceinline__ ushort_t f2bf(float f) {
    union { float f; unsigned u; } v; v.f = f;
    unsigned r = (v.u + 0x7FFFu + ((v.u >> 16) & 1u)) >> 16;
    return (ushort_t)r;
}

__device__ __forceinline__ void gld_lds16(const void* g, void* l) {
    __builtin_amdgcn_global_load_lds((const __attribute__((address_space(1))) void*)g,
                                     (__attribute__((address_space(3))) void*)l, 16, 0, 0);
}

#define BAR()   asm volatile("s_barrier" ::: "memory")
#define WAITV8  do { asm volatile("s_waitcnt vmcnt(8)" ::: "memory"); __builtin_amdgcn_sched_barrier(0); } while (0)
#define WAITV0  do { asm volatile("s_waitcnt vmcnt(0)" ::: "memory"); __builtin_amdgcn_sched_barrier(0); } while (0)
#define WAITL   do { asm volatile("s_waitcnt lgkmcnt(0)" ::: "memory"); __builtin_amdgcn_sched_barrier(0); } while (0)

// ===================== 256x256 8-wave pipelined NT GEMM =====================
// A [M,K] bf16 row-major, B [N,K] bf16 row-major. K multiple of 64, nkt>=2.
// EPI: 2 = scores (*alpha -> bf16 Ch), 3 = PV (+addH+addL+addF -> fp32 Cf)
template<int EPI>
__global__ __launch_bounds__(512, 2)
void mfma_nt256(const ushort_t* __restrict__ A, long long sA, int ldA,
                const ushort_t* __restrict__ B, long long sB, int ldB,
                int N, int K, float alpha,
                ushort_t* __restrict__ Ch, long long sC,
                float* __restrict__ Cf,
                const ushort_t* __restrict__ addH, const ushort_t* __restrict__ addL,
                const float* __restrict__ addF, long long sAdd)
{
    // LDS (ushort units): A half (b,h) at (b*2+h)*8192 ; B half at 32768 + (b*2+h)*8192
    // half = [256 rows][32 k-cols], row = 32 units (64B), chunk = 8 units (16B)
    __shared__ __align__(16) ushort_t lds[65536];

    const int t = threadIdx.x;
    const int w = t >> 6, lane = t & 63;
    const int z = blockIdx.z;
    A += (long long)z * sA;
    B += (long long)z * sB;
    const int m0 = blockIdx.y * 256, n0 = blockIdx.x * 256;
    const int wr = w >> 2, wc = w & 3;           // 2 x 4 wave grid -> wave tile 128x64
    const int fr = lane & 15, kg = lane >> 4;
    const int nkt = K >> 6;

    // staging constants: issue g = w*2+{0,1}; lane covers row g*16+(lane>>2),
    // source chunk pre-swizzled so linear LDS dest == swizzled layout
    const int sRo = lane >> 2;
    const long long sCk = ((lane & 3) ^ ((lane >> 3) & 3)) * 8;
    // frag-read chunk offset (units): chunk kg lives at kg ^ ((row>>1)&3)
    const int co = (kg ^ ((fr >> 1) & 3)) * 8;

#define STAGE(P, base0, ld, segbase, h, Ts) do {                                         \
    const long long kk_ = (long long)(((Ts) < nkt ? (Ts) : (nkt - 1)) * 64 + (h) * 32) + sCk; \
    const int g0_ = w * 2;                                                               \
    gld_lds16((P) + (long long)((base0) + g0_ * 16 + sRo) * (ld) + kk_,                  \
              &lds[(segbase) + g0_ * 512]);                                              \
    gld_lds16((P) + (long long)((base0) + g0_ * 16 + 16 + sRo) * (ld) + kk_,             \
              &lds[(segbase) + g0_ * 512 + 512]);                                        \
} while (0)

#define AREAD(ksseg) do {                                                                \
    const int ab_ = (ksseg) * 8192 + wr * 4096 + fr * 32 + co;                           \
    _Pragma("unroll") for (int fm_ = 0; fm_ < 8; ++fm_)                                  \
        afr[fm_] = *(const short8*)&lds[ab_ + fm_ * 512];                                \
} while (0)

#define BREAD(ksseg, fnh) do {                                                           \
    const int bb_ = 32768 + (ksseg) * 8192 + wc * 2048 + (fnh) * 1024 + fr * 32 + co;    \
    bfr[0] = *(const short8*)&lds[bb_];                                                  \
    bfr[1] = *(const short8*)&lds[bb_ + 512];                                            \
} while (0)

#define MF2(j0) do {                                                                     \
    __builtin_amdgcn_s_setprio(1);                                                       \
    _Pragma("unroll") for (int fm_ = 0; fm_ < 8; ++fm_) {                                \
        acc[fm_][(j0)]     = __builtin_amdgcn_mfma_f32_16x16x32_bf16(afr[fm_], bfr[0], acc[fm_][(j0)], 0, 0, 0);     \
        acc[fm_][(j0) + 1] = __builtin_amdgcn_mfma_f32_16x16x32_bf16(afr[fm_], bfr[1], acc[fm_][(j0) + 1], 0, 0, 0); \
    }                                                                                    \
    __builtin_amdgcn_s_setprio(0);                                                       \
} while (0)

    const f32x4 zero = {0.f, 0.f, 0.f, 0.f};
    f32x4 acc[8][4];
#pragma unroll
    for (int i = 0; i < 8; ++i)
#pragma unroll
        for (int j = 0; j < 4; ++j) acc[i][j] = zero;

    short8 afr[8], bfr[2];

    // prologue: stage A0(0),B0(0),A1(0),B1(0),A0(1),B0(1)  (12 loads in flight)
    STAGE(A, m0, ldA, 0,             0, 0);
    STAGE(B, n0, ldB, 32768,         0, 0);
    STAGE(A, m0, ldA, 8192,          1, 0);
    STAGE(B, n0, ldB, 32768 + 8192,  1, 0);
    STAGE(A, m0, ldA, 16384,         0, 1);
    STAGE(B, n0, ldB, 32768 + 16384, 0, 1);
    // publish tile0-h0: every wave completes its 4 oldest loads (A0h0,B0h0),
    // THEN barrier -> all waves may read any row of that buffer.
    WAITV8;
    BAR();

    for (int kt = 0; kt < nkt; ++kt) {
        const int b = kt & 1, nb = b ^ 1;
        // ---- P1: ks0, fn 0-1 (buffer (b,h0) published by previous WAITV8+BAR) ----
        AREAD(b * 2); BREAD(b * 2, 0);
        STAGE(A, m0, ldA, (nb * 2 + 1) * 8192, 1, kt + 1);
        BAR(); WAITL;
        MF2(0);
        BAR();
        // ---- P2: ks0, fn 2-3 ----
        BREAD(b * 2, 1);
        STAGE(B, n0, ldB, 32768 + (nb * 2 + 1) * 8192, 1, kt + 1);
        BAR(); WAITL;
        MF2(2);
        WAITV8;   // completes (b,h1) pair in every wave, BEFORE the barrier P3 reads behind
        BAR();
        // ---- P3: ks1, fn 0-1 (buffer (b,h1) now published) ----
        AREAD(b * 2 + 1); BREAD(b * 2 + 1, 0);
        STAGE(A, m0, ldA, (b * 2) * 8192, 0, kt + 2);
        BAR(); WAITL;
        MF2(0);
        BAR();
        // ---- P4: ks1, fn 2-3 ----
        BREAD(b * 2 + 1, 1);
        STAGE(B, n0, ldB, 32768 + (b * 2) * 8192, 0, kt + 2);
        BAR(); WAITL;
        MF2(2);
        WAITV8;   // completes next-tile (·,h0) pair, publishing for next P1
        BAR();
    }
    WAITV0;  // drain dummy tail stages before endpgm

    // C/D frag mapping: m = kg*4 + r, n = fr (within 16x16)
#pragma unroll
    for (int fm = 0; fm < 8; ++fm)
#pragma unroll
    for (int fn = 0; fn < 4; ++fn)
#pragma unroll
    for (int r = 0; r < 4; ++r) {
        const int m = m0 + wr * 128 + fm * 16 + kg * 4 + r;
        const int n = n0 + wc * 64 + fn * 16 + fr;
        float v = acc[fm][fn][r];
        const long long idx = (long long)m * N + n;
        if (EPI == 2) {
            Ch[(long long)z * sC + idx] = f2bf(v * alpha);
        } else {
            const long long o = (long long)z * sAdd + idx;
            v += bf2f(addH[o]) + bf2f(addL[o]) + addF[o];
            Cf[o] = v;
        }
    }
#undef STAGE
#undef AREAD
#undef BREAD
#undef MF2
}

// ===================== 128x128 m97-structure NT GEMM (projections) ==========
// EPI: 0=Q(+bias+pos -> bf16), 1=KV(+bias -> hi,lo,T)
template<int AF32, int EPI>
__global__ __launch_bounds__(256)
void mfma_nt(const void* __restrict__ Aptr, long long sA, int ldA,
             const ushort_t* __restrict__ Bh, long long sB, int ldB,
             int N, int K, float alpha,
             const float* __restrict__ bias, const float* __restrict__ pos,
             ushort_t* __restrict__ Ch, ushort_t* __restrict__ Cl, ushort_t* __restrict__ CTh,
             long long sC)
{
    __shared__ __align__(16) ushort_t lds[8192];
    ushort_t* lAh = lds;
    ushort_t* lBh = lds + 4096;

    const int t = threadIdx.x;
    const int w = t >> 6, lane = t & 63;
    const int z = blockIdx.z;
    const ushort_t* Ab = (const ushort_t*)Aptr + (long long)z * sA;
    const float*    Af = (const float*)Aptr    + (long long)z * sA;
    Bh += (long long)z * sB;

    const int m0 = blockIdx.y * 128, n0 = blockIdx.x * 128;
    const int wr = w >> 1, wc = w & 1;
    const int fr = lane & 15, kg = lane >> 4;
    const int srow = lane >> 2;
    const int scol = (lane & 3) * 8;

    const f32x4 zero = {0.f, 0.f, 0.f, 0.f};
    f32x4 acc[4][4];
#pragma unroll
    for (int i = 0; i < 4; ++i)
#pragma unroll
        for (int j = 0; j < 4; ++j) acc[i][j] = zero;

    for (int k0 = 0; k0 < K; k0 += 32) {
#pragma unroll
        for (int i = 0; i < 2; ++i) {
            const int g = w * 2 + i;
            const int row = g * 16 + srow;
            if (AF32) {
                const float* p = Af + (long long)(m0 + row) * ldA + k0 + scol;
                f4 v0 = *(const f4*)p;
                f4 v1 = *(const f4*)(p + 4);
                u16x8 o;
                o[0] = f2bf(v0.x); o[1] = f2bf(v0.y); o[2] = f2bf(v0.z); o[3] = f2bf(v0.w);
                o[4] = f2bf(v1.x); o[5] = f2bf(v1.y); o[6] = f2bf(v1.z); o[7] = f2bf(v1.w);
                *(u16x8*)&lAh[g * 512 + srow * 32 + scol] = o;
            } else {
                gld_lds16(Ab + (long long)(m0 + row) * ldA + k0 + scol, &lAh[g * 512]);
            }
            gld_lds16(Bh + (long long)(n0 + row) * ldB + k0 + scol, &lBh[g * 512]);
        }
        __syncthreads();

        short8 aH[4];
#pragma unroll
        for (int fm = 0; fm < 4; ++fm)
            aH[fm] = *(const short8*)&lAh[(wr * 64 + fm * 16 + fr) * 32 + kg * 8];
#pragma unroll
        for (int fn = 0; fn < 4; ++fn) {
            short8 bH = *(const short8*)&lBh[(wc * 64 + fn * 16 + fr) * 32 + kg * 8];
#pragma unroll
            for (int fm = 0; fm < 4; ++fm)
                acc[fm][fn] = __builtin_amdgcn_mfma_f32_16x16x32_bf16(aH[fm], bH, acc[fm][fn], 0, 0, 0);
        }
        __syncthreads();
    }

#pragma unroll
    for (int fm = 0; fm < 4; ++fm)
#pragma unroll
    for (int fn = 0; fn < 4; ++fn)
#pragma unroll
    for (int r = 0; r < 4; ++r) {
        const int m = m0 + wr * 64 + fm * 16 + kg * 4 + r;
        const int n = n0 + wc * 64 + fn * 16 + fr;
        float v = acc[fm][fn][r];
        const long long idx = (long long)m * N + n;
        if (EPI == 0) {
            v += bias[n] + pos[(long long)(m & 2047) * N + n];
            Ch[idx] = f2bf(v);
        } else {
            v += bias[n];
            ushort_t hi = f2bf(v);
            Ch[idx] = hi;
            Cl[idx] = f2bf(v - bf2f(hi));
            CTh[(long long)(m >> 11) * (512LL * 2048) + (long long)n * 2048 + (m & 2047)] = hi;
        }
    }
}

// two fp32->bf16 conversions (Wq, pw_w), 65536 float4 each
__global__ __launch_bounds__(256)
void cvt2_bf16(const float* __restrict__ a, ushort_t* __restrict__ ao,
               const float* __restrict__ b, ushort_t* __restrict__ bo)
{
    int i = blockIdx.x * 256 + threadIdx.x;
    const float* src = (i < 65536) ? a : b;
    ushort_t* dst = (i < 65536) ? ao : bo;
    int j = i & 65535;
    f4 v = *(const f4*)(src + (long long)j * 4);
    ushort4 o;
    o.x = f2bf(v.x); o.y = f2bf(v.y); o.z = f2bf(v.z); o.w = f2bf(v.w);
    *(ushort4*)&dst[(long long)j * 4] = o;
}

// depthwise conv1d K=6 pad(2,3) + bias, fp32 in -> bf16 out
__global__ __launch_bounds__(256)
void dwconv_bf16(const float* __restrict__ x, const float* __restrict__ w,
                 const float* __restrict__ bias, ushort_t* __restrict__ y)
{
    const int tid = blockIdx.x * 256 + threadIdx.x;
    const int d4 = tid & 127;
    const int rest = tid >> 7;
    const int sc = rest & 255;
    const int b = rest >> 8;
    const int s0 = sc * 8;
    const float* xb = x + ((long long)b * 2048) * 512 + d4 * 4;

    f4 win[13];
#pragma unroll
    for (int j = 0; j < 13; ++j) {
        int r = s0 + j - 2;
        int rc = r < 0 ? 0 : (r > 2047 ? 2047 : r);
        f4 v = *(const f4*)(xb + (long long)rc * 512);
        if (r < 0 || r > 2047) { v.x = 0.f; v.y = 0.f; v.z = 0.f; v.w = 0.f; }
        win[j] = v;
    }
    float wk[4][6];
#pragma unroll
    for (int dd = 0; dd < 4; ++dd)
#pragma unroll
        for (int k = 0; k < 6; ++k) wk[dd][k] = w[(d4 * 4 + dd) * 6 + k];
    const f4 bs4 = *(const f4*)(bias + d4 * 4);

    ushort_t* yb = y + ((long long)b * 2048 + s0) * 512 + d4 * 4;
#pragma unroll
    for (int u = 0; u < 8; ++u) {
        float a0 = bs4.x, a1 = bs4.y, a2 = bs4.z, a3 = bs4.w;
#pragma unroll
        for (int k = 0; k < 6; ++k) {
            f4 v = win[u + k];
            a0 = fmaf(v.x, wk[0][k], a0);
            a1 = fmaf(v.y, wk[1][k], a1);
            a2 = fmaf(v.z, wk[2][k], a2);
            a3 = fmaf(v.w, wk[3][k], a3);
        }
        ushort4 o;
        o.x = f2bf(a0); o.y = f2bf(a1); o.z = f2bf(a2); o.w = f2bf(a3);
        *(ushort4*)(yb + (long long)u * 512) = o;
    }
}

// in-place softmax over bf16 rows of length 2048; one block (256 thr) per row
__global__ __launch_bounds__(256)
void softmax_bf16(ushort_t* __restrict__ p)
{
    ushort_t* row = p + ((long long)blockIdx.x << 11);
    const int t = threadIdx.x;
    __shared__ float redMax[4];
    __shared__ float redSum[4];

    u16x8 u = *(const u16x8*)(row + t * 8);
    float x[8];
#pragma unroll
    for (int i = 0; i < 8; ++i) x[i] = bf2f(u[i]);

    float m = x[0];
#pragma unroll
    for (int i = 1; i < 8; ++i) m = fmaxf(m, x[i]);
#pragma unroll
    for (int off = 32; off > 0; off >>= 1) m = fmaxf(m, __shfl_xor(m, off));
    if ((t & 63) == 0) redMax[t >> 6] = m;
    __syncthreads();
    m = fmaxf(fmaxf(redMax[0], redMax[1]), fmaxf(redMax[2], redMax[3]));

    float e[8], s = 0.f;
#pragma unroll
    for (int i = 0; i < 8; ++i) { e[i] = __expf(x[i] - m); s += e[i]; }
#pragma unroll
    for (int off = 32; off > 0; off >>= 1) s += __shfl_xor(s, off);
    if ((t & 63) == 0) redSum[t >> 6] = s;
    __syncthreads();
    s = (redSum[0] + redSum[1]) + (redSum[2] + redSum[3]);
    const float inv = 1.0f / s;

#pragma unroll
    for (int i = 0; i < 8; ++i) u[i] = f2bf(e[i] * inv);
    *(u16x8*)(row + t * 8) = u;
}

extern "C" void kernel_launch(void* const* d_in, const int* in_sizes, int n_in,
                              void* d_out, int out_size, void* d_ws, size_t ws_size,
                              hipStream_t stream)
{
    const float* evo  = (const float*)d_in[0];
    const float* Wq   = (const float*)d_in[1];
    const float* bq   = (const float*)d_in[2];
    const float* dw_w = (const float*)d_in[3];
    const float* dw_b = (const float*)d_in[4];
    const float* pw_w = (const float*)d_in[5];
    const float* pw_b = (const float*)d_in[6];
    const float* pos  = (const float*)d_in[7];
    float* out = (float*)d_out;

    const long long BSD = 8LL * 2048 * 512;
    const long long DD  = 512LL * 512;
    const long long SD  = 2048LL * 512;
    const long long SS  = 2048LL * 2048;

    ushort_t* QHi  = (ushort_t*)d_ws;
    ushort_t* KVHi = QHi + BSD;
    ushort_t* KVLo = KVHi + BSD;
    ushort_t* KVT  = KVLo + BSD;
    ushort_t* WqB  = KVT + BSD;
    ushort_t* pwB  = WqB + DD;
    ushort_t* X    = pwB + DD;    // dwout, then scores chunks

    long long Xbytes = (long long)ws_size - 68157440LL;
    long long cRaw = Xbytes / (SS * 2);
    int c;
    if (cRaw >= 8) c = 8; else if (cRaw >= 4) c = 4; else if (cRaw >= 2) c = 2; else c = 1;

    ushort_t* dwout = X;

    cvt2_bf16<<<512, 256, 0, stream>>>(Wq, WqB, pw_w, pwB);
    dwconv_bf16<<<1024, 256, 0, stream>>>(evo, dw_w, dw_b, dwout);

    // Q = evo @ Wq^T + bq + pos
    mfma_nt<1, 0><<<dim3(4, 128, 1), 256, 0, stream>>>(
        evo, 0LL, 512, WqB, 0LL, 512, 512, 512, 1.f,
        bq, pos, QHi, nullptr, nullptr, 0LL);

    // KV = dwout @ pw^T + pw_b -> KVhi/KVlo + KVT
    mfma_nt<0, 1><<<dim3(4, 128, 1), 256, 0, stream>>>(
        dwout, 0LL, 512, pwB, 0LL, 512, 512, 512, 1.f,
        pw_b, nullptr, KVHi, KVLo, KVT, 0LL);

    const float scale = 0.04419417382415922f;  // 1/sqrt(512)
    for (int b0 = 0; b0 < 8; b0 += c) {
        const int cc = (8 - b0 < c) ? (8 - b0) : c;
        const long long o = (long long)b0 * SD;
        // scores = scale * Q @ KV^T -> bf16 in X   (256^2 tiles: grid 8x8 per batch)
        mfma_nt256<2><<<dim3(8, 8, cc), 512, 0, stream>>>(
            QHi + o, SD, 512, KVHi + o, SD, 512, 2048, 512, scale,
            X, SS, nullptr, nullptr, nullptr, nullptr, 0LL);
        softmax_bf16<<<cc * 2048, 256, 0, stream>>>(X);
        // out = attn @ KV + (KVhi+KVlo) + evo     (grid 2x8 per batch)
        mfma_nt256<3><<<dim3(2, 8, cc), 512, 0, stream>>>(
            X, SS, 2048, KVT + o, SD, 2048, 512, 2048, 1.f,
            nullptr, 0LL, out + o, KVHi + o, KVLo + o, evo + o, SD);
    }
}

// Round 12
// 284.705 us; speedup vs baseline: 4.2118x; 1.0686x over previous
//
#include <hip/hip_runtime.h>

// CrossAttention B=8,S=2048,D=512 — MFMA bf16.
//  Q  = evo @ Wq^T + bq + pos      (m97-structure kernel, A reg-staged fp32->bf16)
//  KV = dwconv(evo) @ pw^T + pw_b  (m97-structure kernel) -> KVhi, KVT
//  scores = scale * Q @ KV^T (bf16) ; softmax ; out = attn @ KV + KV + evo
//  scores+PV: 256x256-tile 8-wave 4-phase pipelined kernel (r8 race-fixed
//  vmcnt ledger: WAITV8 at END of P2/P4 before the closing barrier).
//  r10: (a) XCD-chunked block swizzle — scores: each XCD owns a 2x4 output
//  region per batch (A-panels fetched by <=1 XCD instead of 8; measured
//  162MB overfetch -> target ~90MB); PV: XCD k owns attn row-strip k.
//  (b) dropped KVLo residual (error budget ~2e-3 << 0.113 threshold) ->
//  X region grows -> c=8 single scores/PV dispatches when ws permits.

typedef unsigned short ushort_t;
typedef __attribute__((ext_vector_type(8))) short short8;
typedef __attribute__((ext_vector_type(8))) unsigned short u16x8;
typedef __attribute__((ext_vector_type(4))) float f32x4;
typedef float4 f4;

__device__ __forceinline__ float bf2f(ushort_t h) {
    union { unsigned u; float f; } v; v.u = ((unsigned)h) << 16; return v.f;
}
__device__ __forceinline__ ushort_t f2bf(float f) {
    union { float f; unsigned u; } v; v.f = f;
    unsigned r = (v.u + 0x7FFFu + ((v.u >> 16) & 1u)) >> 16;
    return (ushort_t)r;
}

__device__ __forceinline__ void gld_lds16(const void* g, void* l) {
    __builtin_amdgcn_global_load_lds((const __attribute__((address_space(1))) void*)g,
                                     (__attribute__((address_space(3))) void*)l, 16, 0, 0);
}

#define BAR()   asm volatile("s_barrier" ::: "memory")
#define WAITV8  do { asm volatile("s_waitcnt vmcnt(8)" ::: "memory"); __builtin_amdgcn_sched_barrier(0); } while (0)
#define WAITV0  do { asm volatile("s_waitcnt vmcnt(0)" ::: "memory"); __builtin_amdgcn_sched_barrier(0); } while (0)
#define WAITL   do { asm volatile("s_waitcnt lgkmcnt(0)" ::: "memory"); __builtin_amdgcn_sched_barrier(0); } while (0)

// ===================== 256x256 8-wave pipelined NT GEMM =====================
// A [M,K] bf16 row-major, B [N,K] bf16 row-major. K multiple of 64, nkt>=2.
// EPI: 2 = scores (*alpha -> bf16 Ch), grid (8,8,cc), XCD 2x4-chunk swizzle
//      3 = PV (+addH+addF -> fp32 Cf), grid (2,8,cc), XCD row-strip swizzle
template<int EPI>
__global__ __launch_bounds__(512, 2)
void mfma_nt256(const ushort_t* __restrict__ A, long long sA, int ldA,
                const ushort_t* __restrict__ B, long long sB, int ldB,
                int N, int K, float alpha,
                ushort_t* __restrict__ Ch, long long sC,
                float* __restrict__ Cf,
                const ushort_t* __restrict__ addH,
                const float* __restrict__ addF, long long sAdd)
{
    // LDS (ushort units): A half (b,h) at (b*2+h)*8192 ; B half at 32768 + (b*2+h)*8192
    __shared__ __align__(16) ushort_t lds[65536];

    const int t = threadIdx.x;
    const int w = t >> 6, lane = t & 63;

    // ---- XCD-chunked swizzle (bijective; XCD model: linear wg id % 8) ----
    int tx, ty, z;
    if (EPI == 2) {
        // grid (8,8,cc): lin = x + 8y + 64z. XCD k owns a 2(y) x 4(x) region per z.
        const int lin = blockIdx.x + (blockIdx.y << 3) + (blockIdx.z << 6);
        const int xcd = lin & 7;
        const int s   = lin >> 3;
        z  = s >> 3;
        const int j = s & 7;
        ty = 2 * (xcd & 3) + (j >> 2);
        tx = 4 * (xcd >> 2) + (j & 3);
    } else {
        // grid (2,8,cc): lin = x + 2y + 16z. XCD k owns attn row-strip y=k (both x).
        const int lin = blockIdx.x + (blockIdx.y << 1) + (blockIdx.z << 4);
        ty = lin & 7;
        tx = (lin >> 3) & 1;
        z  = lin >> 4;
    }
    A += (long long)z * sA;
    B += (long long)z * sB;
    const int m0 = ty * 256, n0 = tx * 256;

    const int wr = w >> 2, wc = w & 3;           // 2 x 4 wave grid -> wave tile 128x64
    const int fr = lane & 15, kg = lane >> 4;
    const int nkt = K >> 6;

    const int sRo = lane >> 2;
    const long long sCk = ((lane & 3) ^ ((lane >> 3) & 3)) * 8;
    const int co = (kg ^ ((fr >> 1) & 3)) * 8;

#define STAGE(P, base0, ld, segbase, h, Ts) do {                                         \
    const long long kk_ = (long long)(((Ts) < nkt ? (Ts) : (nkt - 1)) * 64 + (h) * 32) + sCk; \
    const int g0_ = w * 2;                                                               \
    gld_lds16((P) + (long long)((base0) + g0_ * 16 + sRo) * (ld) + kk_,                  \
              &lds[(segbase) + g0_ * 512]);                                              \
    gld_lds16((P) + (long long)((base0) + g0_ * 16 + 16 + sRo) * (ld) + kk_,             \
              &lds[(segbase) + g0_ * 512 + 512]);                                        \
} while (0)

#define AREAD(ksseg) do {                                                                \
    const int ab_ = (ksseg) * 8192 + wr * 4096 + fr * 32 + co;                           \
    _Pragma("unroll") for (int fm_ = 0; fm_ < 8; ++fm_)                                  \
        afr[fm_] = *(const short8*)&lds[ab_ + fm_ * 512];                                \
} while (0)

#define BREAD(ksseg, fnh) do {                                                           \
    const int bb_ = 32768 + (ksseg) * 8192 + wc * 2048 + (fnh) * 1024 + fr * 32 + co;    \
    bfr[0] = *(const short8*)&lds[bb_];                                                  \
    bfr[1] = *(const short8*)&lds[bb_ + 512];                                            \
} while (0)

#define MF2(j0) do {                                                                     \
    __builtin_amdgcn_s_setprio(1);                                                       \
    _Pragma("unroll") for (int fm_ = 0; fm_ < 8; ++fm_) {                                \
        acc[fm_][(j0)]     = __builtin_amdgcn_mfma_f32_16x16x32_bf16(afr[fm_], bfr[0], acc[fm_][(j0)], 0, 0, 0);     \
        acc[fm_][(j0) + 1] = __builtin_amdgcn_mfma_f32_16x16x32_bf16(afr[fm_], bfr[1], acc[fm_][(j0) + 1], 0, 0, 0); \
    }                                                                                    \
    __builtin_amdgcn_s_setprio(0);                                                       \
} while (0)

    const f32x4 zero = {0.f, 0.f, 0.f, 0.f};
    f32x4 acc[8][4];
#pragma unroll
    for (int i = 0; i < 8; ++i)
#pragma unroll
        for (int j = 0; j < 4; ++j) acc[i][j] = zero;

    short8 afr[8], bfr[2];

    // prologue: stage A0(0),B0(0),A1(0),B1(0),A0(1),B0(1)  (12 loads in flight)
    STAGE(A, m0, ldA, 0,             0, 0);
    STAGE(B, n0, ldB, 32768,         0, 0);
    STAGE(A, m0, ldA, 8192,          1, 0);
    STAGE(B, n0, ldB, 32768 + 8192,  1, 0);
    STAGE(A, m0, ldA, 16384,         0, 1);
    STAGE(B, n0, ldB, 32768 + 16384, 0, 1);
    // publish tile0-h0: every wave completes its 4 oldest loads, THEN barrier.
    WAITV8;
    BAR();

    for (int kt = 0; kt < nkt; ++kt) {
        const int b = kt & 1, nb = b ^ 1;
        // ---- P1: ks0, fn 0-1 ----
        AREAD(b * 2); BREAD(b * 2, 0);
        STAGE(A, m0, ldA, (nb * 2 + 1) * 8192, 1, kt + 1);
        BAR(); WAITL;
        MF2(0);
        BAR();
        // ---- P2: ks0, fn 2-3 ----
        BREAD(b * 2, 1);
        STAGE(B, n0, ldB, 32768 + (nb * 2 + 1) * 8192, 1, kt + 1);
        BAR(); WAITL;
        MF2(2);
        WAITV8;   // publish (b,h1) before the barrier P3 reads behind
        BAR();
        // ---- P3: ks1, fn 0-1 ----
        AREAD(b * 2 + 1); BREAD(b * 2 + 1, 0);
        STAGE(A, m0, ldA, (b * 2) * 8192, 0, kt + 2);
        BAR(); WAITL;
        MF2(0);
        BAR();
        // ---- P4: ks1, fn 2-3 ----
        BREAD(b * 2 + 1, 1);
        STAGE(B, n0, ldB, 32768 + (b * 2) * 8192, 0, kt + 2);
        BAR(); WAITL;
        MF2(2);
        WAITV8;   // publish next-tile (·,h0) for next P1
        BAR();
    }
    WAITV0;  // drain dummy tail stages before endpgm

    // C/D frag mapping: m = kg*4 + r, n = fr (within 16x16)
#pragma unroll
    for (int fm = 0; fm < 8; ++fm)
#pragma unroll
    for (int fn = 0; fn < 4; ++fn)
#pragma unroll
    for (int r = 0; r < 4; ++r) {
        const int m = m0 + wr * 128 + fm * 16 + kg * 4 + r;
        const int n = n0 + wc * 64 + fn * 16 + fr;
        float v = acc[fm][fn][r];
        const long long idx = (long long)m * N + n;
        if (EPI == 2) {
            Ch[(long long)z * sC + idx] = f2bf(v * alpha);
        } else {
            const long long o = (long long)z * sAdd + idx;
            v += bf2f(addH[o]) + addF[o];
            Cf[o] = v;
        }
    }
#undef STAGE
#undef AREAD
#undef BREAD
#undef MF2
}

// ===================== 128x128 m97-structure NT GEMM (projections) ==========
// EPI: 0=Q(+bias+pos -> bf16), 1=KV(+bias -> hi + transposed hi)
template<int AF32, int EPI>
__global__ __launch_bounds__(256)
void mfma_nt(const void* __restrict__ Aptr, long long sA, int ldA,
             const ushort_t* __restrict__ Bh, long long sB, int ldB,
             int N, int K, float alpha,
             const float* __restrict__ bias, const float* __restrict__ pos,
             ushort_t* __restrict__ Ch, ushort_t* __restrict__ CTh,
             long long sC)
{
    __shared__ __align__(16) ushort_t lds[8192];
    ushort_t* lAh = lds;
    ushort_t* lBh = lds + 4096;

    const int t = threadIdx.x;
    const int w = t >> 6, lane = t & 63;
    const int z = blockIdx.z;
    const ushort_t* Ab = (const ushort_t*)Aptr + (long long)z * sA;
    const float*    Af = (const float*)Aptr    + (long long)z * sA;
    Bh += (long long)z * sB;

    const int m0 = blockIdx.y * 128, n0 = blockIdx.x * 128;
    const int wr = w >> 1, wc = w & 1;
    const int fr = lane & 15, kg = lane >> 4;
    const int srow = lane >> 2;
    const int scol = (lane & 3) * 8;

    const f32x4 zero = {0.f, 0.f, 0.f, 0.f};
    f32x4 acc[4][4];
#pragma unroll
    for (int i = 0; i < 4; ++i)
#pragma unroll
        for (int j = 0; j < 4; ++j) acc[i][j] = zero;

    for (int k0 = 0; k0 < K; k0 += 32) {
#pragma unroll
        for (int i = 0; i < 2; ++i) {
            const int g = w * 2 + i;
            const int row = g * 16 + srow;
            if (AF32) {
                const float* p = Af + (long long)(m0 + row) * ldA + k0 + scol;
                f4 v0 = *(const f4*)p;
                f4 v1 = *(const f4*)(p + 4);
                u16x8 o;
                o[0] = f2bf(v0.x); o[1] = f2bf(v0.y); o[2] = f2bf(v0.z); o[3] = f2bf(v0.w);
                o[4] = f2bf(v1.x); o[5] = f2bf(v1.y); o[6] = f2bf(v1.z); o[7] = f2bf(v1.w);
                *(u16x8*)&lAh[g * 512 + srow * 32 + scol] = o;
            } else {
                gld_lds16(Ab + (long long)(m0 + row) * ldA + k0 + scol, &lAh[g * 512]);
            }
            gld_lds16(Bh + (long long)(n0 + row) * ldB + k0 + scol, &lBh[g * 512]);
        }
        __syncthreads();

        short8 aH[4];
#pragma unroll
        for (int fm = 0; fm < 4; ++fm)
            aH[fm] = *(const short8*)&lAh[(wr * 64 + fm * 16 + fr) * 32 + kg * 8];
#pragma unroll
        for (int fn = 0; fn < 4; ++fn) {
            short8 bH = *(const short8*)&lBh[(wc * 64 + fn * 16 + fr) * 32 + kg * 8];
#pragma unroll
            for (int fm = 0; fm < 4; ++fm)
                acc[fm][fn] = __builtin_amdgcn_mfma_f32_16x16x32_bf16(aH[fm], bH, acc[fm][fn], 0, 0, 0);
        }
        __syncthreads();
    }

#pragma unroll
    for (int fm = 0; fm < 4; ++fm)
#pragma unroll
    for (int fn = 0; fn < 4; ++fn)
#pragma unroll
    for (int r = 0; r < 4; ++r) {
        const int m = m0 + wr * 64 + fm * 16 + kg * 4 + r;
        const int n = n0 + wc * 64 + fn * 16 + fr;
        float v = acc[fm][fn][r];
        const long long idx = (long long)m * N + n;
        if (EPI == 0) {
            v += bias[n] + pos[(long long)(m & 2047) * N + n];
            Ch[idx] = f2bf(v);
        } else {
            v += bias[n];
            ushort_t hi = f2bf(v);
            Ch[idx] = hi;
            CTh[(long long)(m >> 11) * (512LL * 2048) + (long long)n * 2048 + (m & 2047)] = hi;
        }
    }
}

// two fp32->bf16 conversions (Wq, pw_w), 65536 float4 each
__global__ __launch_bounds__(256)
void cvt2_bf16(const float* __restrict__ a, ushort_t* __restrict__ ao,
               const float* __restrict__ b, ushort_t* __restrict__ bo)
{
    int i = blockIdx.x * 256 + threadIdx.x;
    const float* src = (i < 65536) ? a : b;
    ushort_t* dst = (i < 65536) ? ao : bo;
    int j = i & 65535;
    f4 v = *(const f4*)(src + (long long)j * 4);
    ushort4 o;
    o.x = f2bf(v.x); o.y = f2bf(v.y); o.z = f2bf(v.z); o.w = f2bf(v.w);
    *(ushort4*)&dst[(long long)j * 4] = o;
}

// depthwise conv1d K=6 pad(2,3) + bias, fp32 in -> bf16 out
__global__ __launch_bounds__(256)
void dwconv_bf16(const float* __restrict__ x, const float* __restrict__ w,
                 const float* __restrict__ bias, ushort_t* __restrict__ y)
{
    const int tid = blockIdx.x * 256 + threadIdx.x;
    const int d4 = tid & 127;
    const int rest = tid >> 7;
    const int sc = rest & 255;
    const int b = rest >> 8;
    const int s0 = sc * 8;
    const float* xb = x + ((long long)b * 2048) * 512 + d4 * 4;

    f4 win[13];
#pragma unroll
    for (int j = 0; j < 13; ++j) {
        int r = s0 + j - 2;
        int rc = r < 0 ? 0 : (r > 2047 ? 2047 : r);
        f4 v = *(const f4*)(xb + (long long)rc * 512);
        if (r < 0 || r > 2047) { v.x = 0.f; v.y = 0.f; v.z = 0.f; v.w = 0.f; }
        win[j] = v;
    }
    float wk[4][6];
#pragma unroll
    for (int dd = 0; dd < 4; ++dd)
#pragma unroll
        for (int k = 0; k < 6; ++k) wk[dd][k] = w[(d4 * 4 + dd) * 6 + k];
    const f4 bs4 = *(const f4*)(bias + d4 * 4);

    ushort_t* yb = y + ((long long)b * 2048 + s0) * 512 + d4 * 4;
#pragma unroll
    for (int u = 0; u < 8; ++u) {
        float a0 = bs4.x, a1 = bs4.y, a2 = bs4.z, a3 = bs4.w;
#pragma unroll
        for (int k = 0; k < 6; ++k) {
            f4 v = win[u + k];
            a0 = fmaf(v.x, wk[0][k], a0);
            a1 = fmaf(v.y, wk[1][k], a1);
            a2 = fmaf(v.z, wk[2][k], a2);
            a3 = fmaf(v.w, wk[3][k], a3);
        }
        ushort4 o;
        o.x = f2bf(a0); o.y = f2bf(a1); o.z = f2bf(a2); o.w = f2bf(a3);
        *(ushort4*)(yb + (long long)u * 512) = o;
    }
}

// in-place softmax over bf16 rows of length 2048; one block (256 thr) per row
__global__ __launch_bounds__(256)
void softmax_bf16(ushort_t* __restrict__ p)
{
    ushort_t* row = p + ((long long)blockIdx.x << 11);
    const int t = threadIdx.x;
    __shared__ float redMax[4];
    __shared__ float redSum[4];

    u16x8 u = *(const u16x8*)(row + t * 8);
    float x[8];
#pragma unroll
    for (int i = 0; i < 8; ++i) x[i] = bf2f(u[i]);

    float m = x[0];
#pragma unroll
    for (int i = 1; i < 8; ++i) m = fmaxf(m, x[i]);
#pragma unroll
    for (int off = 32; off > 0; off >>= 1) m = fmaxf(m, __shfl_xor(m, off));
    if ((t & 63) == 0) redMax[t >> 6] = m;
    __syncthreads();
    m = fmaxf(fmaxf(redMax[0], redMax[1]), fmaxf(redMax[2], redMax[3]));

    float e[8], s = 0.f;
#pragma unroll
    for (int i = 0; i < 8; ++i) { e[i] = __expf(x[i] - m); s += e[i]; }
#pragma unroll
    for (int off = 32; off > 0; off >>= 1) s += __shfl_xor(s, off);
    if ((t & 63) == 0) redSum[t >> 6] = s;
    __syncthreads();
    s = (redSum[0] + redSum[1]) + (redSum[2] + redSum[3]);
    const float inv = 1.0f / s;

#pragma unroll
    for (int i = 0; i < 8; ++i) u[i] = f2bf(e[i] * inv);
    *(u16x8*)(row + t * 8) = u;
}

extern "C" void kernel_launch(void* const* d_in, const int* in_sizes, int n_in,
                              void* d_out, int out_size, void* d_ws, size_t ws_size,
                              hipStream_t stream)
{
    const float* evo  = (const float*)d_in[0];
    const float* Wq   = (const float*)d_in[1];
    const float* bq   = (const float*)d_in[2];
    const float* dw_w = (const float*)d_in[3];
    const float* dw_b = (const float*)d_in[4];
    const float* pw_w = (const float*)d_in[5];
    const float* pw_b = (const float*)d_in[6];
    const float* pos  = (const float*)d_in[7];
    float* out = (float*)d_out;

    const long long BSD = 8LL * 2048 * 512;
    const long long DD  = 512LL * 512;
    const long long SD  = 2048LL * 512;
    const long long SS  = 2048LL * 2048;

    ushort_t* QHi  = (ushort_t*)d_ws;
    ushort_t* KVHi = QHi + BSD;
    ushort_t* KVT  = KVHi + BSD;
    ushort_t* WqB  = KVT + BSD;
    ushort_t* pwB  = WqB + DD;
    ushort_t* X    = pwB + DD;    // dwout, then scores chunks; byte off 51,380,224

    long long Xbytes = (long long)ws_size - 51380224LL;
    long long cRaw = Xbytes / (SS * 2);
    int c;
    if (cRaw >= 8) c = 8; else if (cRaw >= 4) c = 4; else if (cRaw >= 2) c = 2; else c = 1;

    ushort_t* dwout = X;

    cvt2_bf16<<<512, 256, 0, stream>>>(Wq, WqB, pw_w, pwB);
    dwconv_bf16<<<1024, 256, 0, stream>>>(evo, dw_w, dw_b, dwout);

    // Q = evo @ Wq^T + bq + pos
    mfma_nt<1, 0><<<dim3(4, 128, 1), 256, 0, stream>>>(
        evo, 0LL, 512, WqB, 0LL, 512, 512, 512, 1.f,
        bq, pos, QHi, nullptr, 0LL);

    // KV = dwout @ pw^T + pw_b -> KVhi + KVT
    mfma_nt<0, 1><<<dim3(4, 128, 1), 256, 0, stream>>>(
        dwout, 0LL, 512, pwB, 0LL, 512, 512, 512, 1.f,
        pw_b, nullptr, KVHi, KVT, 0LL);

    const float scale = 0.04419417382415922f;  // 1/sqrt(512)
    for (int b0 = 0; b0 < 8; b0 += c) {
        const int cc = (8 - b0 < c) ? (8 - b0) : c;
        const long long o = (long long)b0 * SD;
        // scores = scale * Q @ KV^T -> bf16 in X  (XCD 2x4-chunk swizzle)
        mfma_nt256<2><<<dim3(8, 8, cc), 512, 0, stream>>>(
            QHi + o, SD, 512, KVHi + o, SD, 512, 2048, 512, scale,
            X, SS, nullptr, nullptr, nullptr, 0LL);
        softmax_bf16<<<cc * 2048, 256, 0, stream>>>(X);
        // out = attn @ KV + KV + evo  (XCD row-strip swizzle)
        mfma_nt256<3><<<dim3(2, 8, cc), 512, 0, stream>>>(
            X, SS, 2048, KVT + o, SD, 2048, 512, 2048, 1.f,
            nullptr, 0LL, out + o, KVHi + o, evo + o, SD);
    }
}

// Round 13
// 273.103 us; speedup vs baseline: 4.3907x; 1.0425x over previous
//
#include <hip/hip_runtime.h>

// CrossAttention B=8,S=2048,D=512 — MFMA bf16.
//  Q  = evo @ Wq^T + bq + pos      (m97-structure kernel, A reg-staged fp32->bf16)
//  KV = dwconv(evo) @ pw^T + pw_b  (m97-structure kernel) -> KVhi, KVT
//  scores = scale * Q @ KV^T (bf16, 256^2 4-phase pipelined, XCD 2x4 swizzle)
//  softmax: one wave per row (no LDS, no barriers)
//  PV: out = attn @ KV + KV + evo  — r13: 128x256-tile variant (mfma_pv128):
//    grid 2x16x8 = 256 blocks (1/CU, was 128 = half machine idle, r12 counters:
//    Occupancy 10%, MfmaUtil 18%, HBM 28% — coverage-bound). 4-phase schedule,
//    vmcnt ledger re-derived: STAGE_A=1 load, STAGE_B=2 -> prologue 9, WAITV6
//    publishes each (A,B) half-pair at END of P2/P4 (r8-proven pattern).
//    XCD k <-> batch k swizzle (KVT 2MB + attn stream L2-local per XCD).

typedef unsigned short ushort_t;
typedef __attribute__((ext_vector_type(8))) short short8;
typedef __attribute__((ext_vector_type(8))) unsigned short u16x8;
typedef __attribute__((ext_vector_type(4))) float f32x4;
typedef float4 f4;

__device__ __forceinline__ float bf2f(ushort_t h) {
    union { unsigned u; float f; } v; v.u = ((unsigned)h) << 16; return v.f;
}
__device__ __forceinline__ ushort_t f2bf(float f) {
    union { float f; unsigned u; } v; v.f = f;
    unsigned r = (v.u + 0x7FFFu + ((v.u >> 16) & 1u)) >> 16;
    return (ushort_t)r;
}

__device__ __forceinline__ void gld_lds16(const void* g, void* l) {
    __builtin_amdgcn_global_load_lds((const __attribute__((address_space(1))) void*)g,
                                     (__attribute__((address_space(3))) void*)l, 16, 0, 0);
}

#define BAR()   asm volatile("s_barrier" ::: "memory")
#define WAITV8  do { asm volatile("s_waitcnt vmcnt(8)" ::: "memory"); __builtin_amdgcn_sched_barrier(0); } while (0)
#define WAITV6  do { asm volatile("s_waitcnt vmcnt(6)" ::: "memory"); __builtin_amdgcn_sched_barrier(0); } while (0)
#define WAITV0  do { asm volatile("s_waitcnt vmcnt(0)" ::: "memory"); __builtin_amdgcn_sched_barrier(0); } while (0)
#define WAITL   do { asm volatile("s_waitcnt lgkmcnt(0)" ::: "memory"); __builtin_amdgcn_sched_barrier(0); } while (0)

// ===================== 256x256 8-wave pipelined NT GEMM (scores) ============
// A [M,K] bf16 row-major, B [N,K] bf16 row-major. EPI 2: *alpha -> bf16 Ch.
template<int EPI>
__global__ __launch_bounds__(512, 2)
void mfma_nt256(const ushort_t* __restrict__ A, long long sA, int ldA,
                const ushort_t* __restrict__ B, long long sB, int ldB,
                int N, int K, float alpha,
                ushort_t* __restrict__ Ch, long long sC,
                float* __restrict__ Cf,
                const ushort_t* __restrict__ addH,
                const float* __restrict__ addF, long long sAdd)
{
    __shared__ __align__(16) ushort_t lds[65536];

    const int t = threadIdx.x;
    const int w = t >> 6, lane = t & 63;

    // XCD 2x4-chunk swizzle: grid (8,8,cc), lin%8 = XCD owns 2(y)x4(x) region per z.
    int tx, ty, z;
    {
        const int lin = blockIdx.x + (blockIdx.y << 3) + (blockIdx.z << 6);
        const int xcd = lin & 7;
        const int s   = lin >> 3;
        z  = s >> 3;
        const int j = s & 7;
        ty = 2 * (xcd & 3) + (j >> 2);
        tx = 4 * (xcd >> 2) + (j & 3);
    }
    A += (long long)z * sA;
    B += (long long)z * sB;
    const int m0 = ty * 256, n0 = tx * 256;

    const int wr = w >> 2, wc = w & 3;
    const int fr = lane & 15, kg = lane >> 4;
    const int nkt = K >> 6;

    const int sRo = lane >> 2;
    const long long sCk = ((lane & 3) ^ ((lane >> 3) & 3)) * 8;
    const int co = (kg ^ ((fr >> 1) & 3)) * 8;

#define STAGE(P, base0, ld, segbase, h, Ts) do {                                         \
    const long long kk_ = (long long)(((Ts) < nkt ? (Ts) : (nkt - 1)) * 64 + (h) * 32) + sCk; \
    const int g0_ = w * 2;                                                               \
    gld_lds16((P) + (long long)((base0) + g0_ * 16 + sRo) * (ld) + kk_,                  \
              &lds[(segbase) + g0_ * 512]);                                              \
    gld_lds16((P) + (long long)((base0) + g0_ * 16 + 16 + sRo) * (ld) + kk_,             \
              &lds[(segbase) + g0_ * 512 + 512]);                                        \
} while (0)

#define AREAD(ksseg) do {                                                                \
    const int ab_ = (ksseg) * 8192 + wr * 4096 + fr * 32 + co;                           \
    _Pragma("unroll") for (int fm_ = 0; fm_ < 8; ++fm_)                                  \
        afr[fm_] = *(const short8*)&lds[ab_ + fm_ * 512];                                \
} while (0)

#define BREAD(ksseg, fnh) do {                                                           \
    const int bb_ = 32768 + (ksseg) * 8192 + wc * 2048 + (fnh) * 1024 + fr * 32 + co;    \
    bfr[0] = *(const short8*)&lds[bb_];                                                  \
    bfr[1] = *(const short8*)&lds[bb_ + 512];                                            \
} while (0)

#define MF2(j0) do {                                                                     \
    __builtin_amdgcn_s_setprio(1);                                                       \
    _Pragma("unroll") for (int fm_ = 0; fm_ < 8; ++fm_) {                                \
        acc[fm_][(j0)]     = __builtin_amdgcn_mfma_f32_16x16x32_bf16(afr[fm_], bfr[0], acc[fm_][(j0)], 0, 0, 0);     \
        acc[fm_][(j0) + 1] = __builtin_amdgcn_mfma_f32_16x16x32_bf16(afr[fm_], bfr[1], acc[fm_][(j0) + 1], 0, 0, 0); \
    }                                                                                    \
    __builtin_amdgcn_s_setprio(0);                                                       \
} while (0)

    const f32x4 zero = {0.f, 0.f, 0.f, 0.f};
    f32x4 acc[8][4];
#pragma unroll
    for (int i = 0; i < 8; ++i)
#pragma unroll
        for (int j = 0; j < 4; ++j) acc[i][j] = zero;

    short8 afr[8], bfr[2];

    STAGE(A, m0, ldA, 0,             0, 0);
    STAGE(B, n0, ldB, 32768,         0, 0);
    STAGE(A, m0, ldA, 8192,          1, 0);
    STAGE(B, n0, ldB, 32768 + 8192,  1, 0);
    STAGE(A, m0, ldA, 16384,         0, 1);
    STAGE(B, n0, ldB, 32768 + 16384, 0, 1);
    WAITV8;
    BAR();

    for (int kt = 0; kt < nkt; ++kt) {
        const int b = kt & 1, nb = b ^ 1;
        AREAD(b * 2); BREAD(b * 2, 0);
        STAGE(A, m0, ldA, (nb * 2 + 1) * 8192, 1, kt + 1);
        BAR(); WAITL;
        MF2(0);
        BAR();
        BREAD(b * 2, 1);
        STAGE(B, n0, ldB, 32768 + (nb * 2 + 1) * 8192, 1, kt + 1);
        BAR(); WAITL;
        MF2(2);
        WAITV8;
        BAR();
        AREAD(b * 2 + 1); BREAD(b * 2 + 1, 0);
        STAGE(A, m0, ldA, (b * 2) * 8192, 0, kt + 2);
        BAR(); WAITL;
        MF2(0);
        BAR();
        BREAD(b * 2 + 1, 1);
        STAGE(B, n0, ldB, 32768 + (b * 2) * 8192, 0, kt + 2);
        BAR(); WAITL;
        MF2(2);
        WAITV8;
        BAR();
    }
    WAITV0;

#pragma unroll
    for (int fm = 0; fm < 8; ++fm)
#pragma unroll
    for (int fn = 0; fn < 4; ++fn)
#pragma unroll
    for (int r = 0; r < 4; ++r) {
        const int m = m0 + wr * 128 + fm * 16 + kg * 4 + r;
        const int n = n0 + wc * 64 + fn * 16 + fr;
        const long long idx = (long long)m * N + n;
        Ch[(long long)z * sC + idx] = f2bf(acc[fm][fn][r] * alpha);
    }
#undef STAGE
#undef AREAD
#undef BREAD
#undef MF2
}

// ===================== 128x256 8-wave pipelined PV GEMM =====================
// A=attn [M=2048,K=2048] bf16, B=KVT [N=512,K=2048] bf16; wave tile 64x64.
// LDS: A half (s) at s*4096 (128x32), B half (s) at 16384 + s*8192 (256x32).
// Ledger: STAGE_A=1 load, STAGE_B=2; prologue 9 outstanding, WAITV6 at end of
// P2/P4 publishes the (A,B) half-pair (3 loads) before the barrier.
__global__ __launch_bounds__(512, 1)
void mfma_pv128(const ushort_t* __restrict__ A, long long sA, int ldA,
                const ushort_t* __restrict__ B, long long sB, int ldB,
                int N, int K,
                float* __restrict__ Cf,
                const ushort_t* __restrict__ addH,
                const float* __restrict__ addF, long long sAdd)
{
    __shared__ __align__(16) ushort_t lds[49152];

    const int t = threadIdx.x;
    const int w = t >> 6, lane = t & 63;

    // XCD k <-> batch k (grid (2,16,8): 32 blocks per z = one XCD's share).
    int tx, ty, z;
    const int lin = blockIdx.x + (blockIdx.y << 1) + (blockIdx.z << 5);
    if (gridDim.z == 8) {
        z = lin & 7;
        const int j = lin >> 3;   // 0..31
        ty = j >> 1;
        tx = j & 1;
    } else {
        tx = blockIdx.x; ty = blockIdx.y; z = blockIdx.z;
    }
    A += (long long)z * sA;
    B += (long long)z * sB;
    const int m0 = ty * 128, n0 = tx * 256;

    const int wr = w >> 2, wc = w & 3;           // 2 x 4 waves -> wave tile 64x64
    const int fr = lane & 15, kg = lane >> 4;
    const int nkt = K >> 6;                       // 32

    const int sRo = lane >> 2;
    const long long sCk = ((lane & 3) ^ ((lane >> 3) & 3)) * 8;
    const int co = (kg ^ ((fr >> 1) & 3)) * 8;

#define SA_(seg, h, Ts) do {                                                             \
    const long long kk_ = (long long)(((Ts) < nkt ? (Ts) : (nkt - 1)) * 64 + (h) * 32) + sCk; \
    gld_lds16(A + (long long)(m0 + w * 16 + sRo) * ldA + kk_,                            \
              &lds[(seg) * 4096 + w * 512]);                                             \
} while (0)

#define SB_(seg, h, Ts) do {                                                             \
    const long long kk_ = (long long)(((Ts) < nkt ? (Ts) : (nkt - 1)) * 64 + (h) * 32) + sCk; \
    const int g0_ = w * 2;                                                               \
    gld_lds16(B + (long long)(n0 + g0_ * 16 + sRo) * ldB + kk_,                          \
              &lds[16384 + (seg) * 8192 + g0_ * 512]);                                   \
    gld_lds16(B + (long long)(n0 + g0_ * 16 + 16 + sRo) * ldB + kk_,                     \
              &lds[16384 + (seg) * 8192 + g0_ * 512 + 512]);                             \
} while (0)

#define AR_(seg) do {                                                                    \
    const int ab_ = (seg) * 4096 + wr * 2048 + fr * 32 + co;                             \
    _Pragma("unroll") for (int fm_ = 0; fm_ < 4; ++fm_)                                  \
        afr[fm_] = *(const short8*)&lds[ab_ + fm_ * 512];                                \
} while (0)

#define BR_(seg, fnh) do {                                                               \
    const int bb_ = 16384 + (seg) * 8192 + wc * 2048 + (fnh) * 1024 + fr * 32 + co;      \
    bfr[0] = *(const short8*)&lds[bb_];                                                  \
    bfr[1] = *(const short8*)&lds[bb_ + 512];                                            \
} while (0)

#define MF8(j0) do {                                                                     \
    __builtin_amdgcn_s_setprio(1);                                                       \
    _Pragma("unroll") for (int fm_ = 0; fm_ < 4; ++fm_) {                                \
        acc[fm_][(j0)]     = __builtin_amdgcn_mfma_f32_16x16x32_bf16(afr[fm_], bfr[0], acc[fm_][(j0)], 0, 0, 0);     \
        acc[fm_][(j0) + 1] = __builtin_amdgcn_mfma_f32_16x16x32_bf16(afr[fm_], bfr[1], acc[fm_][(j0) + 1], 0, 0, 0); \
    }                                                                                    \
    __builtin_amdgcn_s_setprio(0);                                                       \
} while (0)

    const f32x4 zero = {0.f, 0.f, 0.f, 0.f};
    f32x4 acc[4][4];
#pragma unroll
    for (int i = 0; i < 4; ++i)
#pragma unroll
        for (int j = 0; j < 4; ++j) acc[i][j] = zero;

    short8 afr[4], bfr[2];

    // prologue: A(0,h0),B(0,h0), A(0,h1),B(0,h1), A(1,h0),B(1,h0) = 9 loads
    SA_(0, 0, 0); SB_(0, 0, 0);
    SA_(1, 1, 0); SB_(1, 1, 0);
    SA_(2, 0, 1); SB_(2, 0, 1);
    WAITV6;   // publish (0,h0): completes 3 oldest (A+2B)
    BAR();

    for (int kt = 0; kt < nkt; ++kt) {
        const int b = kt & 1, nb = b ^ 1;
        // P1
        AR_(b * 2); BR_(b * 2, 0);
        SA_(nb * 2 + 1, 1, kt + 1);
        BAR(); WAITL;
        MF8(0);
        BAR();
        // P2
        BR_(b * 2, 1);
        SB_(nb * 2 + 1, 1, kt + 1);
        BAR(); WAITL;
        MF8(2);
        WAITV6;   // publish (b,h1)
        BAR();
        // P3
        AR_(b * 2 + 1); BR_(b * 2 + 1, 0);
        SA_(b * 2, 0, kt + 2);
        BAR(); WAITL;
        MF8(0);
        BAR();
        // P4
        BR_(b * 2 + 1, 1);
        SB_(b * 2, 0, kt + 2);
        BAR(); WAITL;
        MF8(2);
        WAITV6;   // publish next-tile (·,h0)
        BAR();
    }
    WAITV0;

#pragma unroll
    for (int fm = 0; fm < 4; ++fm)
#pragma unroll
    for (int fn = 0; fn < 4; ++fn)
#pragma unroll
    for (int r = 0; r < 4; ++r) {
        const int m = m0 + wr * 64 + fm * 16 + kg * 4 + r;
        const int n = n0 + wc * 64 + fn * 16 + fr;
        const long long o = (long long)z * sAdd + (long long)m * N + n;
        Cf[o] = acc[fm][fn][r] + bf2f(addH[o]) + addF[o];
    }
#undef SA_
#undef SB_
#undef AR_
#undef BR_
#undef MF8
}

// ===================== 128x128 m97-structure NT GEMM (projections) ==========
template<int AF32, int EPI>
__global__ __launch_bounds__(256)
void mfma_nt(const void* __restrict__ Aptr, long long sA, int ldA,
             const ushort_t* __restrict__ Bh, long long sB, int ldB,
             int N, int K, float alpha,
             const float* __restrict__ bias, const float* __restrict__ pos,
             ushort_t* __restrict__ Ch, ushort_t* __restrict__ CTh,
             long long sC)
{
    __shared__ __align__(16) ushort_t lds[8192];
    ushort_t* lAh = lds;
    ushort_t* lBh = lds + 4096;

    const int t = threadIdx.x;
    const int w = t >> 6, lane = t & 63;
    const int z = blockIdx.z;
    const ushort_t* Ab = (const ushort_t*)Aptr + (long long)z * sA;
    const float*    Af = (const float*)Aptr    + (long long)z * sA;
    Bh += (long long)z * sB;

    const int m0 = blockIdx.y * 128, n0 = blockIdx.x * 128;
    const int wr = w >> 1, wc = w & 1;
    const int fr = lane & 15, kg = lane >> 4;
    const int srow = lane >> 2;
    const int scol = (lane & 3) * 8;

    const f32x4 zero = {0.f, 0.f, 0.f, 0.f};
    f32x4 acc[4][4];
#pragma unroll
    for (int i = 0; i < 4; ++i)
#pragma unroll
        for (int j = 0; j < 4; ++j) acc[i][j] = zero;

    for (int k0 = 0; k0 < K; k0 += 32) {
#pragma unroll
        for (int i = 0; i < 2; ++i) {
            const int g = w * 2 + i;
            const int row = g * 16 + srow;
            if (AF32) {
                const float* p = Af + (long long)(m0 + row) * ldA + k0 + scol;
                f4 v0 = *(const f4*)p;
                f4 v1 = *(const f4*)(p + 4);
                u16x8 o;
                o[0] = f2bf(v0.x); o[1] = f2bf(v0.y); o[2] = f2bf(v0.z); o[3] = f2bf(v0.w);
                o[4] = f2bf(v1.x); o[5] = f2bf(v1.y); o[6] = f2bf(v1.z); o[7] = f2bf(v1.w);
                *(u16x8*)&lAh[g * 512 + srow * 32 + scol] = o;
            } else {
                gld_lds16(Ab + (long long)(m0 + row) * ldA + k0 + scol, &lAh[g * 512]);
            }
            gld_lds16(Bh + (long long)(n0 + row) * ldB + k0 + scol, &lBh[g * 512]);
        }
        __syncthreads();

        short8 aH[4];
#pragma unroll
        for (int fm = 0; fm < 4; ++fm)
            aH[fm] = *(const short8*)&lAh[(wr * 64 + fm * 16 + fr) * 32 + kg * 8];
#pragma unroll
        for (int fn = 0; fn < 4; ++fn) {
            short8 bH = *(const short8*)&lBh[(wc * 64 + fn * 16 + fr) * 32 + kg * 8];
#pragma unroll
            for (int fm = 0; fm < 4; ++fm)
                acc[fm][fn] = __builtin_amdgcn_mfma_f32_16x16x32_bf16(aH[fm], bH, acc[fm][fn], 0, 0, 0);
        }
        __syncthreads();
    }

#pragma unroll
    for (int fm = 0; fm < 4; ++fm)
#pragma unroll
    for (int fn = 0; fn < 4; ++fn)
#pragma unroll
    for (int r = 0; r < 4; ++r) {
        const int m = m0 + wr * 64 + fm * 16 + kg * 4 + r;
        const int n = n0 + wc * 64 + fn * 16 + fr;
        float v = acc[fm][fn][r];
        const long long idx = (long long)m * N + n;
        if (EPI == 0) {
            v += bias[n] + pos[(long long)(m & 2047) * N + n];
            Ch[idx] = f2bf(v);
        } else {
            v += bias[n];
            ushort_t hi = f2bf(v);
            Ch[idx] = hi;
            CTh[(long long)(m >> 11) * (512LL * 2048) + (long long)n * 2048 + (m & 2047)] = hi;
        }
    }
}

// two fp32->bf16 conversions (Wq, pw_w), 65536 float4 each
__global__ __launch_bounds__(256)
void cvt2_bf16(const float* __restrict__ a, ushort_t* __restrict__ ao,
               const float* __restrict__ b, ushort_t* __restrict__ bo)
{
    int i = blockIdx.x * 256 + threadIdx.x;
    const float* src = (i < 65536) ? a : b;
    ushort_t* dst = (i < 65536) ? ao : bo;
    int j = i & 65535;
    f4 v = *(const f4*)(src + (long long)j * 4);
    ushort4 o;
    o.x = f2bf(v.x); o.y = f2bf(v.y); o.z = f2bf(v.z); o.w = f2bf(v.w);
    *(ushort4*)&dst[(long long)j * 4] = o;
}

// depthwise conv1d K=6 pad(2,3) + bias, fp32 in -> bf16 out
__global__ __launch_bounds__(256)
void dwconv_bf16(const float* __restrict__ x, const float* __restrict__ w,
                 const float* __restrict__ bias, ushort_t* __restrict__ y)
{
    const int tid = blockIdx.x * 256 + threadIdx.x;
    const int d4 = tid & 127;
    const int rest = tid >> 7;
    const int sc = rest & 255;
    const int b = rest >> 8;
    const int s0 = sc * 8;
    const float* xb = x + ((long long)b * 2048) * 512 + d4 * 4;

    f4 win[13];
#pragma unroll
    for (int j = 0; j < 13; ++j) {
        int r = s0 + j - 2;
        int rc = r < 0 ? 0 : (r > 2047 ? 2047 : r);
        f4 v = *(const f4*)(xb + (long long)rc * 512);
        if (r < 0 || r > 2047) { v.x = 0.f; v.y = 0.f; v.z = 0.f; v.w = 0.f; }
        win[j] = v;
    }
    float wk[4][6];
#pragma unroll
    for (int dd = 0; dd < 4; ++dd)
#pragma unroll
        for (int k = 0; k < 6; ++k) wk[dd][k] = w[(d4 * 4 + dd) * 6 + k];
    const f4 bs4 = *(const f4*)(bias + d4 * 4);

    ushort_t* yb = y + ((long long)b * 2048 + s0) * 512 + d4 * 4;
#pragma unroll
    for (int u = 0; u < 8; ++u) {
        float a0 = bs4.x, a1 = bs4.y, a2 = bs4.z, a3 = bs4.w;
#pragma unroll
        for (int k = 0; k < 6; ++k) {
            f4 v = win[u + k];
            a0 = fmaf(v.x, wk[0][k], a0);
            a1 = fmaf(v.y, wk[1][k], a1);
            a2 = fmaf(v.z, wk[2][k], a2);
            a3 = fmaf(v.w, wk[3][k], a3);
        }
        ushort4 o;
        o.x = f2bf(a0); o.y = f2bf(a1); o.z = f2bf(a2); o.w = f2bf(a3);
        *(ushort4*)(yb + (long long)u * 512) = o;
    }
}

// softmax: ONE WAVE PER ROW (length 2048: 32 elems/lane), 4 rows per block.
// No LDS, no __syncthreads.
__global__ __launch_bounds__(256)
void softmax_wave(ushort_t* __restrict__ p)
{
    const int t = threadIdx.x;
    const int w = t >> 6, lane = t & 63;
    ushort_t* row = p + (((long long)blockIdx.x * 4 + w) << 11);

    u16x8 u[4];
    float x[32];
#pragma unroll
    for (int i = 0; i < 4; ++i) {
        u[i] = *(const u16x8*)(row + i * 512 + lane * 8);
#pragma unroll
        for (int j = 0; j < 8; ++j) x[i * 8 + j] = bf2f(u[i][j]);
    }

    float m = x[0];
#pragma unroll
    for (int i = 1; i < 32; ++i) m = fmaxf(m, x[i]);
#pragma unroll
    for (int off = 32; off > 0; off >>= 1) m = fmaxf(m, __shfl_xor(m, off));

    float s = 0.f;
#pragma unroll
    for (int i = 0; i < 32; ++i) { x[i] = __expf(x[i] - m); s += x[i]; }
#pragma unroll
    for (int off = 32; off > 0; off >>= 1) s += __shfl_xor(s, off);
    const float inv = 1.0f / s;

#pragma unroll
    for (int i = 0; i < 4; ++i) {
#pragma unroll
        for (int j = 0; j < 8; ++j) u[i][j] = f2bf(x[i * 8 + j] * inv);
        *(u16x8*)(row + i * 512 + lane * 8) = u[i];
    }
}

extern "C" void kernel_launch(void* const* d_in, const int* in_sizes, int n_in,
                              void* d_out, int out_size, void* d_ws, size_t ws_size,
                              hipStream_t stream)
{
    const float* evo  = (const float*)d_in[0];
    const float* Wq   = (const float*)d_in[1];
    const float* bq   = (const float*)d_in[2];
    const float* dw_w = (const float*)d_in[3];
    const float* dw_b = (const float*)d_in[4];
    const float* pw_w = (const float*)d_in[5];
    const float* pw_b = (const float*)d_in[6];
    const float* pos  = (const float*)d_in[7];
    float* out = (float*)d_out;

    const long long BSD = 8LL * 2048 * 512;
    const long long DD  = 512LL * 512;
    const long long SD  = 2048LL * 512;
    const long long SS  = 2048LL * 2048;

    ushort_t* QHi  = (ushort_t*)d_ws;
    ushort_t* KVHi = QHi + BSD;
    ushort_t* KVT  = KVHi + BSD;
    ushort_t* WqB  = KVT + BSD;
    ushort_t* pwB  = WqB + DD;
    ushort_t* X    = pwB + DD;    // dwout, then scores chunks; byte off 51,380,224

    long long Xbytes = (long long)ws_size - 51380224LL;
    long long cRaw = Xbytes / (SS * 2);
    int c;
    if (cRaw >= 8) c = 8; else if (cRaw >= 4) c = 4; else if (cRaw >= 2) c = 2; else c = 1;

    ushort_t* dwout = X;

    cvt2_bf16<<<512, 256, 0, stream>>>(Wq, WqB, pw_w, pwB);
    dwconv_bf16<<<1024, 256, 0, stream>>>(evo, dw_w, dw_b, dwout);

    // Q = evo @ Wq^T + bq + pos
    mfma_nt<1, 0><<<dim3(4, 128, 1), 256, 0, stream>>>(
        evo, 0LL, 512, WqB, 0LL, 512, 512, 512, 1.f,
        bq, pos, QHi, nullptr, 0LL);

    // KV = dwout @ pw^T + pw_b -> KVhi + KVT
    mfma_nt<0, 1><<<dim3(4, 128, 1), 256, 0, stream>>>(
        dwout, 0LL, 512, pwB, 0LL, 512, 512, 512, 1.f,
        pw_b, nullptr, KVHi, KVT, 0LL);

    const float scale = 0.04419417382415922f;  // 1/sqrt(512)
    for (int b0 = 0; b0 < 8; b0 += c) {
        const int cc = (8 - b0 < c) ? (8 - b0) : c;
        const long long o = (long long)b0 * SD;
        // scores = scale * Q @ KV^T -> bf16 in X  (XCD 2x4-chunk swizzle)
        mfma_nt256<2><<<dim3(8, 8, cc), 512, 0, stream>>>(
            QHi + o, SD, 512, KVHi + o, SD, 512, 2048, 512, scale,
            X, SS, nullptr, nullptr, nullptr, 0LL);
        // softmax: wave-per-row
        softmax_wave<<<cc * 512, 256, 0, stream>>>(X);
        // out = attn @ KV + KV + evo  (128x256 tiles, 256 blocks, XCD=batch)
        mfma_pv128<<<dim3(2, 16, cc), 512, 0, stream>>>(
            X, SS, 2048, KVT + o, SD, 2048, 512, 2048,
            out + o, KVHi + o, evo + o, SD);
    }
}